// Round 4
// baseline (1031.558 us; speedup 1.0000x reference)
//
#include <hip/hip_runtime.h>
#include <hip/hip_bf16.h>

#define NC 4096
#define GG 1024
#define DM 128
#define HDIM 32
#define FF 512
#define LL 2
#define NHCI 2
#define LS2 (100.0f*100.0f)

typedef __bf16 bf16x8 __attribute__((ext_vector_type(8)));
typedef __bf16 bf16x4 __attribute__((ext_vector_type(4)));
typedef float  f32x4  __attribute__((ext_vector_type(4)));

// bijective XCD-chunk swizzle (m204): launch-id -> semantic tile id such that
// each XCD (launch%8) owns a contiguous semantic chunk.
__device__ __forceinline__ int xcd_swz(int orig, int nwg)
{
    int q = nwg >> 3, r = nwg & 7;
    int xcd = orig & 7, idx = orig >> 3;
    return (xcd < r ? xcd*(q+1) : r*(q+1) + (xcd-r)*q) + idx;
}

// ================= bf16 MFMA GEMM (m97 structure, fused epilogues) ==========
enum { MM_NONE=0, MM_BIAS, MM_BIAS_B16, MM_RELU_B16, MM_B16, MM_SIGSP_B16 };

template<int EM>
__launch_bounds__(256)
__global__ void mgemm_k(const __bf16* __restrict__ A, int lda,
                        const __bf16* __restrict__ BT, int ldb,
                        const float* __restrict__ bias,
                        float* __restrict__ C, __bf16* __restrict__ Cb, int ldc,
                        int M, int N, int K, float alpha,
                        const float* __restrict__ spd,
                        const int* __restrict__ flag)
{
    if (flag && *flag == 0) return;
    __shared__ __align__(16) __bf16 As[128][32];
    __shared__ __align__(16) __bf16 Bs[128][32];
    const int tid  = threadIdx.x;
    const int lane = tid & 63;
    const int wid  = tid >> 6;
    const int wm = wid >> 1, wn = wid & 1;
    const int nwg  = gridDim.x * gridDim.y;
    const int wg   = xcd_swz(blockIdx.y * gridDim.x + blockIdx.x, nwg);
    const int bm = (wg / gridDim.x) * 128, bn = (wg % gridDim.x) * 128;

    f32x4 acc[4][4];
    #pragma unroll
    for (int m=0;m<4;m++)
        #pragma unroll
        for (int n=0;n<4;n++) acc[m][n] = (f32x4){0.f,0.f,0.f,0.f};

    const int c0 = wid*64 + lane, c1 = c0 + 256;
    const __bf16* ga0 = A  + (size_t)(bm + (c0>>2))*lda + ((c0&3)<<3);
    const __bf16* ga1 = A  + (size_t)(bm + (c1>>2))*lda + ((c1&3)<<3);
    const __bf16* gb0 = BT + (size_t)(bn + (c0>>2))*ldb + ((c0&3)<<3);
    const __bf16* gb1 = BT + (size_t)(bn + (c1>>2))*ldb + ((c1&3)<<3);
    auto* lA = (__attribute__((address_space(3))) __bf16*)&As[0][0];
    auto* lB = (__attribute__((address_space(3))) __bf16*)&Bs[0][0];
    auto* lA0 = (__attribute__((address_space(3))) void*)(lA + (size_t)(wid*64)*8);
    auto* lA1 = (__attribute__((address_space(3))) void*)(lA + (size_t)(256 + wid*64)*8);
    auto* lB0 = (__attribute__((address_space(3))) void*)(lB + (size_t)(wid*64)*8);
    auto* lB1 = (__attribute__((address_space(3))) void*)(lB + (size_t)(256 + wid*64)*8);

    const int r  = lane & 15;
    const int kb = lane >> 4;
    const int arow = wm*64, brow = wn*64;

    for (int k0 = 0; k0 < K; k0 += 32) {
        __builtin_amdgcn_global_load_lds((const __attribute__((address_space(1))) void*)ga0, lA0, 16, 0, 0);
        __builtin_amdgcn_global_load_lds((const __attribute__((address_space(1))) void*)ga1, lA1, 16, 0, 0);
        __builtin_amdgcn_global_load_lds((const __attribute__((address_space(1))) void*)gb0, lB0, 16, 0, 0);
        __builtin_amdgcn_global_load_lds((const __attribute__((address_space(1))) void*)gb1, lB1, 16, 0, 0);
        ga0 += 32; ga1 += 32; gb0 += 32; gb1 += 32;
        __syncthreads();
        bf16x8 af[4], bfr[4];
        #pragma unroll
        for (int m=0;m<4;m++) af[m]  = *(const bf16x8*)&As[arow + m*16 + r][kb*8];
        #pragma unroll
        for (int n=0;n<4;n++) bfr[n] = *(const bf16x8*)&Bs[brow + n*16 + r][kb*8];
        #pragma unroll
        for (int m=0;m<4;m++)
            #pragma unroll
            for (int n=0;n<4;n++)
                acc[m][n] = __builtin_amdgcn_mfma_f32_16x16x32_bf16(af[m], bfr[n], acc[m][n], 0, 0, 0);
        __syncthreads();
    }

    const int crow = (lane >> 4) * 4;
    const int ccol = lane & 15;
    #pragma unroll
    for (int m=0;m<4;m++) {
        #pragma unroll
        for (int n=0;n<4;n++) {
            const int gn = bn + wn*64 + n*16 + ccol;
            #pragma unroll
            for (int q=0;q<4;q++) {
                const int gm = bm + wm*64 + m*16 + crow + q;
                float v = acc[m][n][q] * alpha;
                if (EM==MM_BIAS || EM==MM_BIAS_B16 || EM==MM_RELU_B16) v += bias[gn];
                if (EM==MM_RELU_B16) v = fmaxf(v, 0.f);
                if (EM==MM_SIGSP_B16) {
                    v = 1.f/(1.f + __expf(-v));
                    v *= __expf(spd[(size_t)gm*(size_t)N + gn] * (-1.f/LS2));
                }
                const size_t ci = (size_t)gm*ldc + gn;
                if (EM==MM_NONE || EM==MM_BIAS) C[ci] = v;
                else Cb[ci] = (__bf16)v;
            }
        }
    }
}

// ================= split-K MFMA GEMM: partials to P[ks][M][N] fp32 ==========
__launch_bounds__(256)
__global__ void mgemm_sk(const __bf16* __restrict__ A, int lda,
                         const __bf16* __restrict__ BT, int ldb,
                         float* __restrict__ P, int M, int N, int KC,
                         const int* __restrict__ flag)
{
    if (flag && *flag == 0) return;
    __shared__ __align__(16) __bf16 As[128][32];
    __shared__ __align__(16) __bf16 Bs[128][32];
    const int tid  = threadIdx.x;
    const int lane = tid & 63;
    const int wid  = tid >> 6;
    const int wm = wid >> 1, wn = wid & 1;
    const int nwg  = gridDim.x * gridDim.y;
    const int wg   = xcd_swz(blockIdx.y * gridDim.x + blockIdx.x, nwg);
    const int bm = (wg / gridDim.x) * 128, bn = (wg % gridDim.x) * 128;
    const size_t koff = (size_t)blockIdx.z * KC;

    f32x4 acc[4][4];
    #pragma unroll
    for (int m=0;m<4;m++)
        #pragma unroll
        for (int n=0;n<4;n++) acc[m][n] = (f32x4){0.f,0.f,0.f,0.f};

    const int c0 = wid*64 + lane, c1 = c0 + 256;
    const __bf16* ga0 = A  + (size_t)(bm + (c0>>2))*lda + koff + ((c0&3)<<3);
    const __bf16* ga1 = A  + (size_t)(bm + (c1>>2))*lda + koff + ((c1&3)<<3);
    const __bf16* gb0 = BT + (size_t)(bn + (c0>>2))*ldb + koff + ((c0&3)<<3);
    const __bf16* gb1 = BT + (size_t)(bn + (c1>>2))*ldb + koff + ((c1&3)<<3);
    auto* lA = (__attribute__((address_space(3))) __bf16*)&As[0][0];
    auto* lB = (__attribute__((address_space(3))) __bf16*)&Bs[0][0];
    auto* lA0 = (__attribute__((address_space(3))) void*)(lA + (size_t)(wid*64)*8);
    auto* lA1 = (__attribute__((address_space(3))) void*)(lA + (size_t)(256 + wid*64)*8);
    auto* lB0 = (__attribute__((address_space(3))) void*)(lB + (size_t)(wid*64)*8);
    auto* lB1 = (__attribute__((address_space(3))) void*)(lB + (size_t)(256 + wid*64)*8);

    const int r  = lane & 15;
    const int kb = lane >> 4;
    const int arow = wm*64, brow = wn*64;

    for (int k0 = 0; k0 < KC; k0 += 32) {
        __builtin_amdgcn_global_load_lds((const __attribute__((address_space(1))) void*)ga0, lA0, 16, 0, 0);
        __builtin_amdgcn_global_load_lds((const __attribute__((address_space(1))) void*)ga1, lA1, 16, 0, 0);
        __builtin_amdgcn_global_load_lds((const __attribute__((address_space(1))) void*)gb0, lB0, 16, 0, 0);
        __builtin_amdgcn_global_load_lds((const __attribute__((address_space(1))) void*)gb1, lB1, 16, 0, 0);
        ga0 += 32; ga1 += 32; gb0 += 32; gb1 += 32;
        __syncthreads();
        bf16x8 af[4], bfr[4];
        #pragma unroll
        for (int m=0;m<4;m++) af[m]  = *(const bf16x8*)&As[arow + m*16 + r][kb*8];
        #pragma unroll
        for (int n=0;n<4;n++) bfr[n] = *(const bf16x8*)&Bs[brow + n*16 + r][kb*8];
        #pragma unroll
        for (int m=0;m<4;m++)
            #pragma unroll
            for (int n=0;n<4;n++)
                acc[m][n] = __builtin_amdgcn_mfma_f32_16x16x32_bf16(af[m], bfr[n], acc[m][n], 0, 0, 0);
        __syncthreads();
    }

    float* Pz = P + (size_t)blockIdx.z * M * N;
    const int crow = (lane >> 4) * 4;
    const int ccol = lane & 15;
    #pragma unroll
    for (int m=0;m<4;m++)
        #pragma unroll
        for (int n=0;n<4;n++) {
            const int gn = bn + wn*64 + n*16 + ccol;
            #pragma unroll
            for (int q=0;q<4;q++) {
                const int gm = bm + wm*64 + m*16 + crow + q;
                Pz[(size_t)gm*N + gn] = acc[m][n][q];
            }
        }
}

// ================= split-K reduce with fused epilogues ======================
enum { R_F32=0, R_B16LD, R_ACCG, R_RELU_B16, R_BIASRES, R_TANH, R_BOTH };

template<int RE>
__launch_bounds__(256)
__global__ void redk_k(const float* __restrict__ P, int M, int N, int KS,
                       const float* __restrict__ bias,
                       const float* __restrict__ res, int ldres,
                       float* __restrict__ C, __bf16* __restrict__ Cb,
                       int ldout, int coff,
                       const int* __restrict__ flag, float alpha)
{
    if (flag && *flag == 0) return;
    int i = blockIdx.x*256 + threadIdx.x;       // group of 4 elements
    int total = (M*N) >> 2;
    if (i >= total) return;
    int row = i / (N >> 2);
    int c4  = (i - row*(N >> 2)) << 2;
    f32x4 s = *(const f32x4*)(P + (size_t)row*N + c4);
    for (int ks = 1; ks < KS; ++ks)
        s += *(const f32x4*)(P + ((size_t)ks*M + row)*N + c4);
    #pragma unroll
    for (int j=0;j<4;j++) {
        int col = c4 + j;
        float v = s[j];
        if (RE==R_RELU_B16) v = fmaxf(v + bias[col], 0.f);
        if (RE==R_BIASRES)  v = v + bias[col] + res[(size_t)row*ldres + col];
        if (RE==R_TANH)     v = tanhf(v + bias[col]);
        if (RE==R_BOTH)     v = v + bias[col];
        size_t o = (size_t)row*ldout + coff + col;
        if (RE==R_F32 || RE==R_BIASRES || RE==R_TANH) C[o] = v;
        if (RE==R_BOTH) { C[o] = v; Cb[o] = (__bf16)v; }
        if (RE==R_B16LD || RE==R_RELU_B16) Cb[o] = (__bf16)v;
        if (RE==R_ACCG) C[o] += v * alpha;
    }
}

// ================= fused flash attention =================
__launch_bounds__(256)
__global__ void flash_k(const __bf16* __restrict__ Q, const __bf16* __restrict__ Kb,
                        int ldqk, const __bf16* __restrict__ VT, __bf16* __restrict__ O)
{
    __shared__ __align__(16) __bf16 Plds[4][16][72];
    const int lane = threadIdx.x & 63, w = threadIdx.x >> 6;
    const int hd = blockIdx.y;
    const int q0 = blockIdx.x * 64 + w * 16;
    const int c  = lane & 15, kb = lane >> 4;
    const float scale = 0.17677669529663687f;

    const bf16x8 aq = *(const bf16x8*)&Q[(size_t)(q0 + c)*ldqk + hd*HDIM + kb*8];
    float m[4], l[4];
    #pragma unroll
    for (int q=0;q<4;q++) { m[q] = -3.0e38f; l[q] = 0.f; }
    f32x4 oacc[2] = {(f32x4){0,0,0,0}, (f32x4){0,0,0,0}};

    for (int kv = 0; kv < NC; kv += 64) {
        f32x4 s[4];
        #pragma unroll
        for (int n=0;n<4;n++) {
            bf16x8 bk = *(const bf16x8*)&Kb[(size_t)(kv + n*16 + c)*ldqk + hd*HDIM + kb*8];
            s[n] = __builtin_amdgcn_mfma_f32_16x16x32_bf16(aq, bk, (f32x4){0,0,0,0}, 0, 0, 0);
        }
        float f[4];
        #pragma unroll
        for (int q=0;q<4;q++) {
            float t = fmaxf(fmaxf(s[0][q], s[1][q]), fmaxf(s[2][q], s[3][q]));
            #pragma unroll
            for (int o=1;o<16;o<<=1) t = fmaxf(t, __shfl_xor(t, o));
            float nm = fmaxf(m[q], t * scale);
            f[q] = __expf(m[q] - nm);
            m[q] = nm;
        }
        float psum[4] = {0.f,0.f,0.f,0.f};
        #pragma unroll
        for (int n=0;n<4;n++) {
            #pragma unroll
            for (int q=0;q<4;q++) {
                float p = __expf(s[n][q]*scale - m[q]);
                psum[q] += p;
                Plds[w][kb*4+q][n*16+c] = (__bf16)p;
            }
        }
        #pragma unroll
        for (int q=0;q<4;q++) {
            float t = psum[q];
            #pragma unroll
            for (int o=1;o<16;o<<=1) t += __shfl_xor(t, o);
            l[q] = l[q]*f[q] + t;
            oacc[0][q] *= f[q];
            oacc[1][q] *= f[q];
        }
        #pragma unroll
        for (int ks=0;ks<2;ks++) {
            bf16x8 ap = *(const bf16x8*)&Plds[w][c][ks*32 + kb*8];
            #pragma unroll
            for (int n2=0;n2<2;n2++) {
                bf16x8 bv = *(const bf16x8*)&VT[(size_t)(hd*HDIM + n2*16 + c)*NC + kv + ks*32 + kb*8];
                oacc[n2] = __builtin_amdgcn_mfma_f32_16x16x32_bf16(ap, bv, oacc[n2], 0, 0, 0);
            }
        }
    }
    #pragma unroll
    for (int n2=0;n2<2;n2++)
        #pragma unroll
        for (int q=0;q<4;q++)
            O[(size_t)(q0 + kb*4 + q)*DM + hd*HDIM + n2*16 + c] = (__bf16)(oacc[n2][q] / l[q]);
}

// ================= small kernels =================
__global__ void qualify2_k(const float* __restrict__ Tq, const float* __restrict__ w,
                           const float* __restrict__ b2, float* __restrict__ quality)
{
    int row = blockIdx.x, lane = threadIdx.x;
    float v = Tq[row*128 + lane] * w[lane];
    #pragma unroll
    for (int o=32;o>0;o>>=1) v += __shfl_down(v, o);
    if (lane == 0) quality[row] = v + b2[0];
}

__global__ void qw1pad_k(const float* __restrict__ W, __bf16* __restrict__ out)
{
    int idx = blockIdx.x*256 + threadIdx.x;
    int k = idx & 1023, j = idx >> 10;
    out[(size_t)j*GG + k] = (j < 64) ? (__bf16)W[(size_t)k*64 + j] : (__bf16)0.f;
}

__global__ void padb_k(const float* __restrict__ b, float* __restrict__ out)
{
    int i = threadIdx.x;
    out[i] = (i < 64) ? b[i] : 0.f;
}

// pack [Wq^T;Wk^T;Wv^T] -> WT[l][384][128], biases -> bb[l][384]
__global__ void qkvpack_k(const float* __restrict__ Wq, const float* __restrict__ Wk,
                          const float* __restrict__ Wv,
                          const float* __restrict__ bq, const float* __restrict__ bk,
                          const float* __restrict__ bv,
                          __bf16* __restrict__ WT, float* __restrict__ bb)
{
    int l = blockIdx.y;
    int i = blockIdx.x*256 + threadIdx.x;   // < 384*128
    int n = i >> 7, k = i & 127;
    const float* W = (n < 128) ? Wq : (n < 256 ? Wk : Wv);
    int nn = n & 127;
    WT[(size_t)l*384*128 + i] = (__bf16)W[(size_t)l*DM*DM + (size_t)k*DM + nn];
    if (i < 384) {
        const float* b = (i < 128) ? bq : (i < 256 ? bk : bv);
        bb[l*384 + i] = b[l*DM + (i & 127)];
    }
}

__global__ void rownorm_k(const float* __restrict__ h, float* __restrict__ sq)
{
    int row = blockIdx.x, lane = threadIdx.x;
    float x0 = h[row*DM + lane], x1 = h[row*DM + lane + 64];
    float v = x0*x0 + x1*x1;
    #pragma unroll
    for (int o=32;o>0;o>>=1) v += __shfl_down(v, o);
    if (lane == 0) sq[row] = v;
}

__global__ void add_ln_k(float* __restrict__ h, __bf16* __restrict__ hb,
                         const float* __restrict__ t,
                         const float* __restrict__ g, const float* __restrict__ b)
{
    int row = blockIdx.x, lane = threadIdx.x;
    float x0 = h[row*DM + lane]      + t[row*DM + lane];
    float x1 = h[row*DM + lane + 64] + t[row*DM + lane + 64];
    float s = x0 + x1, ss = x0*x0 + x1*x1;
    #pragma unroll
    for (int o=32;o>0;o>>=1) { s += __shfl_down(s, o); ss += __shfl_down(ss, o); }
    s = __shfl(s, 0); ss = __shfl(ss, 0);
    float mean = s * (1.f/128.f);
    float var  = ss * (1.f/128.f) - mean*mean;
    float inv  = rsqrtf(var + 1e-5f);
    float y0 = g[lane]      * (x0 - mean) * inv + b[lane];
    float y1 = g[lane + 64] * (x1 - mean) * inv + b[lane + 64];
    h[row*DM + lane]       = y0;  h[row*DM + lane + 64]  = y1;
    hb[row*DM + lane]      = (__bf16)y0;
    hb[row*DM + lane + 64] = (__bf16)y1;
}

__launch_bounds__(256)
__global__ void dist_softmax_k(const float* __restrict__ Sg, const float* __restrict__ sqv,
                               const float* __restrict__ qual, __bf16* __restrict__ P, int W)
{
    __shared__ float sm[4], sl[4];
    size_t row = blockIdx.x;
    const float* p = Sg + row * (size_t)W;
    __bf16* po = P + row * (size_t)W;
    int tid = threadIdx.x;
    float sqi = sqv[row];
    float m = -3.0e38f, l = 0.f;
    for (int j = tid; j < W; j += 256) {
        float d2 = fmaxf(sqi + sqv[j] - 2.f * p[j], 0.f);
        float lg = -sqrtf(d2) + qual[j];
        float mn = fmaxf(m, lg);
        l = l * __expf(m - mn) + __expf(lg - mn);
        m = mn;
    }
    #pragma unroll
    for (int o=32;o>0;o>>=1) {
        float m2 = __shfl_down(m, o), l2 = __shfl_down(l, o);
        float mn = fmaxf(m, m2);
        l = l * __expf(m - mn) + l2 * __expf(m2 - mn);
        m = mn;
    }
    if ((tid & 63) == 0) { sm[tid >> 6] = m; sl[tid >> 6] = l; }
    __syncthreads();
    m = sm[0]; l = sl[0];
    #pragma unroll
    for (int i=1;i<4;i++) {
        float mn = fmaxf(m, sm[i]);
        l = l * __expf(m - mn) + sl[i] * __expf(sm[i] - mn);
        m = mn;
    }
    float inv = 1.f / l;
    for (int j = tid; j < W; j += 256) {
        float d2 = fmaxf(sqi + sqv[j] - 2.f * p[j], 0.f);
        float lg = -sqrtf(d2) + qual[j];
        po[j] = (__bf16)(__expf(lg - m) * inv);
    }
}

// fp32 [R][C] -> bf16 transposed, out[(c)*ldout + coff + r]
__global__ void tconv_ld_k(const float* __restrict__ in, __bf16* __restrict__ out,
                           int R, int C, int ldout, int coff,
                           const int* __restrict__ flag)
{
    if (flag && *flag == 0) return;
    __shared__ float tile[32][33];
    int bc = blockIdx.x * 32, br = blockIdx.y * 32;
    int tx = threadIdx.x & 31, ty = threadIdx.x >> 5;
    #pragma unroll
    for (int i=0;i<4;i++)
        tile[ty + 8*i][tx] = in[(size_t)(br + ty + 8*i)*C + bc + tx];
    __syncthreads();
    #pragma unroll
    for (int i=0;i<4;i++)
        out[(size_t)(bc + ty + 8*i)*ldout + coff + br + tx] = (__bf16)tile[tx][ty + 8*i];
}

// bf16 [R][ldin] cols [coff, coff+C) -> bf16 [C][R]
__global__ void tconv16_k(const __bf16* __restrict__ in, int ldin, int coff,
                          __bf16* __restrict__ out, int R)
{
    __shared__ __bf16 tile[32][33];
    int bc = blockIdx.x * 32, br = blockIdx.y * 32;
    int tx = threadIdx.x & 31, ty = threadIdx.x >> 5;
    #pragma unroll
    for (int i=0;i<4;i++)
        tile[ty + 8*i][tx] = in[(size_t)(br + ty + 8*i)*ldin + coff + bc + tx];
    __syncthreads();
    #pragma unroll
    for (int i=0;i<4;i++)
        out[(size_t)(bc + ty + 8*i)*R + br + tx] = tile[tx][ty + 8*i];
}

__global__ void conv_k(const float* __restrict__ in, __bf16* __restrict__ out, int n4)
{
    int i = blockIdx.x * 256 + threadIdx.x;
    if (i < n4) {
        float4 v = ((const float4*)in)[i];
        bf16x4 o = {(__bf16)v.x, (__bf16)v.y, (__bf16)v.z, (__bf16)v.w};
        ((bf16x4*)out)[i] = o;
    }
}

// ================= launchers =================
static void mg(int em, const __bf16* A, int lda, const __bf16* BT, int ldb,
               const float* bias, float* C, __bf16* Cb, int ldc,
               int M, int N, int K, float alpha,
               const float* spd, const int* flag, hipStream_t s)
{
    dim3 grid(N/128, M/128), block(256);
#define MGL(E) mgemm_k<E><<<grid,block,0,s>>>(A,lda,BT,ldb,bias,C,Cb,ldc,M,N,K,alpha,spd,flag)
    switch (em) {
        case MM_NONE:      MGL(MM_NONE);      break;
        case MM_BIAS:      MGL(MM_BIAS);      break;
        case MM_BIAS_B16:  MGL(MM_BIAS_B16);  break;
        case MM_RELU_B16:  MGL(MM_RELU_B16);  break;
        case MM_B16:       MGL(MM_B16);       break;
        case MM_SIGSP_B16: MGL(MM_SIGSP_B16); break;
    }
#undef MGL
}

static void sk(const __bf16* A, int lda, const __bf16* BT, int ldb,
               float* P, int M, int N, int K, int KS, const int* flag, hipStream_t s)
{
    dim3 grid(N/128, M/128, KS), block(256);
    mgemm_sk<<<grid, block, 0, s>>>(A, lda, BT, ldb, P, M, N, K/KS, flag);
}

static void red(int re, const float* P, int M, int N, int KS,
                const float* bias, const float* res, int ldres,
                float* C, __bf16* Cb, int ldout, int coff,
                const int* flag, float alpha, hipStream_t s)
{
    int blocks = (M*N/4 + 255) / 256;
#define RDL(E) redk_k<E><<<blocks,256,0,s>>>(P,M,N,KS,bias,res,ldres,C,Cb,ldout,coff,flag,alpha)
    switch (re) {
        case R_F32:      RDL(R_F32);      break;
        case R_B16LD:    RDL(R_B16LD);    break;
        case R_ACCG:     RDL(R_ACCG);     break;
        case R_RELU_B16: RDL(R_RELU_B16); break;
        case R_BIASRES:  RDL(R_BIASRES);  break;
        case R_TANH:     RDL(R_TANH);     break;
        case R_BOTH:     RDL(R_BOTH);     break;
    }
#undef RDL
}

static void tc(const float* in, __bf16* out, int R, int C, const int* flag, hipStream_t s)
{
    dim3 grid(C/32, R/32), block(256);
    tconv_ld_k<<<grid, block, 0, s>>>(in, out, R, C, R, 0, flag);
}

extern "C" void kernel_launch(void* const* d_in, const int* in_sizes, int n_in,
                              void* d_out, int out_size, void* d_ws, size_t ws_size,
                              hipStream_t stream)
{
    const float* raw   = (const float*)d_in[0];
    const float* spd   = (const float*)d_in[1];
    const float* dn_W1 = (const float*)d_in[2];
    const float* dn_b1 = (const float*)d_in[3];
    const float* dn_W2 = (const float*)d_in[4];
    const float* dn_b2 = (const float*)d_in[5];
    const float* q_W1  = (const float*)d_in[6];
    const float* q_b1  = (const float*)d_in[7];
    const float* q_W2  = (const float*)d_in[8];
    const float* q_b2  = (const float*)d_in[9];
    const float* e_Win = (const float*)d_in[10];
    const float* e_bin = (const float*)d_in[11];
    const float* Wq    = (const float*)d_in[12];
    const float* Wk    = (const float*)d_in[13];
    const float* Wv    = (const float*)d_in[14];
    const float* Wo    = (const float*)d_in[15];
    const float* bq    = (const float*)d_in[16];
    const float* bk    = (const float*)d_in[17];
    const float* bv    = (const float*)d_in[18];
    const float* bo    = (const float*)d_in[19];
    const float* ln1_g = (const float*)d_in[20];
    const float* ln1_b = (const float*)d_in[21];
    const float* ln2_g = (const float*)d_in[22];
    const float* ln2_b = (const float*)d_in[23];
    const float* f_W1  = (const float*)d_in[24];
    const float* f_b1  = (const float*)d_in[25];
    const float* f_W2  = (const float*)d_in[26];
    const float* f_b2  = (const float*)d_in[27];
    const float* ci_T  = (const float*)d_in[28];
    const float* ci_G  = (const float*)d_in[29];
    const int*   interact = (const int*)d_in[30];
    (void)in_sizes; (void)n_in; (void)ws_size; (void)out_size;

    float* out = (float*)d_out;
    float* ws = (float*)d_ws;
    size_t off = 0;
    auto af32 = [&](size_t n) { float* p = ws + off; off += n; return p; };
    auto ab16 = [&](size_t n) { __bf16* p = (__bf16*)(ws + off); off += (n + 1) / 2; return p; };

    float*  S        = af32((size_t)NC * NC);   // gram fp32; reused as split-K partial buffer
    float*  denoised = af32((size_t)NC * GG);
    __bf16* simB     = ab16((size_t)NC * NC);
    __bf16* ciS      = ab16((size_t)NC * NC);   // CI sigmoid*spatial (per head, reused)
    __bf16* T1b      = ab16((size_t)NC * FF);
    float*  Tq       = af32((size_t)NC * 128);
    float*  quality  = af32(NC);
    float*  h        = af32((size_t)NC * DM);
    __bf16* hb       = ab16((size_t)NC * DM);
    __bf16* qkvB     = ab16((size_t)NC * 384);
    __bf16* vbT      = ab16((size_t)DM * NC);
    __bf16* obB      = ab16((size_t)NC * DM);
    float*  t2       = af32((size_t)NC * DM);
    __bf16* rawB     = ab16((size_t)NC * GG);
    __bf16* denT     = ab16((size_t)GG * NC);
    __bf16* smoT     = ab16((size_t)GG * NC);
    __bf16* Ubig     = ab16((size_t)NC * 2*GG); // [4096][2048] CI K-concat
    __bf16* TembB    = ab16((size_t)NC * DM);
    float*  sqbuf    = af32(NC);
    __bf16* dnW1T    = ab16((size_t)FF * GG);
    __bf16* dnW2T    = ab16((size_t)GG * FF);
    __bf16* eWinT    = ab16((size_t)DM * GG);
    __bf16* qW1pT    = ab16((size_t)128 * GG);
    float*  qb1p     = af32(128);
    __bf16* Wqkv     = ab16((size_t)LL * 384 * DM);
    float*  bqkv     = af32((size_t)LL * 384);
    __bf16* WoT      = ab16((size_t)LL * DM * DM);
    __bf16* fW1T     = ab16((size_t)LL * FF * DM);
    __bf16* fW2T     = ab16((size_t)LL * DM * FF);
    __bf16* ciTT     = ab16((size_t)NHCI * DM * DM);
    __bf16* ciGbigT  = ab16((size_t)GG * 2*GG);  // [1024][2048]

    // ---- packs / conversions ----
    tc(dn_W1, dnW1T, GG, FF, nullptr, stream);
    tc(dn_W2, dnW2T, FF, GG, nullptr, stream);
    tc(e_Win, eWinT, GG, DM, nullptr, stream);
    qw1pad_k<<<(128*GG)/256, 256, 0, stream>>>(q_W1, qW1pT);
    padb_k<<<1, 128, 0, stream>>>(q_b1, qb1p);
    qkvpack_k<<<dim3(192, LL), 256, 0, stream>>>(Wq, Wk, Wv, bq, bk, bv, Wqkv, bqkv);
    for (int l = 0; l < LL; ++l) {
        tc(Wo + (size_t)l*DM*DM, WoT + (size_t)l*DM*DM, DM, DM, nullptr, stream);
        tc(f_W1 + (size_t)l*DM*FF, fW1T + (size_t)l*FF*DM, DM, FF, nullptr, stream);
        tc(f_W2 + (size_t)l*FF*DM, fW2T + (size_t)l*DM*FF, FF, DM, nullptr, stream);
    }
    conv_k<<<(NC*GG/4 + 255)/256, 256, 0, stream>>>(raw, rawB, NC*GG/4);

    // ---- CellDenoise (split-K) ----
    sk(rawB, GG, dnW1T, GG, S, NC, FF, GG, 8, nullptr, stream);
    red(R_RELU_B16, S, NC, FF, 8, dn_b1, nullptr, 0, nullptr, T1b, FF, 0, nullptr, 1.f, stream);
    sk(T1b, FF, dnW2T, FF, S, NC, GG, FF, 4, nullptr, stream);
    red(R_BIASRES, S, NC, GG, 4, dn_b2, raw, GG, denoised, nullptr, GG, 0, nullptr, 1.f, stream);
    // ---- CellQualify (split-K, padded N=128) ----
    sk(rawB, GG, qW1pT, GG, S, NC, 128, GG, 8, nullptr, stream);
    red(R_TANH, S, NC, 128, 8, qb1p, nullptr, 0, Tq, nullptr, 128, 0, nullptr, 1.f, stream);
    qualify2_k<<<NC, 64, 0, stream>>>(Tq, q_W2, q_b2, quality);
    // ---- CellEmbed input proj (split-K) ----
    sk(rawB, GG, eWinT, GG, S, NC, 128, GG, 8, nullptr, stream);
    red(R_BOTH, S, NC, 128, 8, e_bin, nullptr, 0, h, hb, 128, 0, nullptr, 1.f, stream);
    // ---- Transformer layers ----
    for (int l = 0; l < LL; ++l) {
        mg(MM_BIAS_B16, hb, DM, Wqkv + (size_t)l*384*DM, DM, bqkv + l*384,
           nullptr, qkvB, 384, NC, 384, DM, 1.f, nullptr, nullptr, stream);
        tconv16_k<<<dim3(DM/32, NC/32), 256, 0, stream>>>(qkvB, 384, 256, vbT, NC);
        flash_k<<<dim3(NC/64, 4), 256, 0, stream>>>(qkvB, qkvB + 128, 384, vbT, obB);
        mg(MM_BIAS, obB, DM, WoT + (size_t)l*DM*DM, DM, bo + l*DM,
           t2, nullptr, DM, NC, DM, DM, 1.f, nullptr, nullptr, stream);
        add_ln_k<<<NC, 64, 0, stream>>>(h, hb, t2, ln1_g + l*DM, ln1_b + l*DM);
        mg(MM_RELU_B16, hb, DM, fW1T + (size_t)l*FF*DM, DM, f_b1 + l*FF,
           nullptr, T1b, FF, NC, FF, DM, 1.f, nullptr, nullptr, stream);
        mg(MM_BIAS, T1b, FF, fW2T + (size_t)l*DM*FF, FF, f_b2 + l*DM,
           t2, nullptr, DM, NC, DM, FF, 1.f, nullptr, nullptr, stream);
        add_ln_k<<<NC, 64, 0, stream>>>(h, hb, t2, ln2_g + l*DM, ln2_b + l*DM);
    }
    // ---- CellSmooth ----
    rownorm_k<<<NC, 64, 0, stream>>>(h, sqbuf);
    mg(MM_NONE, hb, DM, hb, DM, nullptr, S, nullptr, NC, NC, NC, DM, 1.f, nullptr, nullptr, stream);
    dist_softmax_k<<<NC, 256, 0, stream>>>(S, sqbuf, quality, simB, NC);
    tc(denoised, denT, NC, GG, nullptr, stream);
    sk(simB, NC, denT, NC, S, NC, GG, NC, 4, nullptr, stream);
    red(R_F32, S, NC, GG, 4, nullptr, nullptr, 0, out, nullptr, GG, 0, nullptr, 1.f, stream);
    // ---- CellInteract (gated on *interact) ----
    tc(out, smoT, NC, GG, interact, stream);
    for (int hh = 0; hh < NHCI; ++hh) {
        tc(ci_T + (size_t)hh*DM*DM, ciTT + (size_t)hh*DM*DM, DM, DM, interact, stream);
        // ciGbigT[n][hh*1024 + kk] = ci_G[hh][kk][n]
        dim3 gg(GG/32, GG/32);
        tconv_ld_k<<<gg, 256, 0, stream>>>(ci_G + (size_t)hh*GG*GG, ciGbigT, GG, GG,
                                           2*GG, hh*GG, interact);
    }
    for (int hh = 0; hh < NHCI; ++hh) {
        mg(MM_B16, hb, DM, ciTT + (size_t)hh*DM*DM, DM, nullptr,
           nullptr, TembB, DM, NC, DM, DM, 1.f, nullptr, interact, stream);
        mg(MM_SIGSP_B16, TembB, DM, hb, DM, nullptr,
           nullptr, ciS, NC, NC, NC, DM, 1.f, spd, interact, stream);
        sk(ciS, NC, smoT, NC, S, NC, GG, NC, 4, interact, stream);
        red(R_B16LD, S, NC, GG, 4, nullptr, nullptr, 0, nullptr, Ubig, 2*GG, hh*GG,
            interact, 1.f, stream);
    }
    sk(Ubig, 2*GG, ciGbigT, 2*GG, S, NC, GG, 2*GG, 4, interact, stream);
    red(R_ACCG, S, NC, GG, 4, nullptr, nullptr, 0, out, nullptr, GG, 0,
        interact, 1.0f/1024.f, stream);
}

// Round 5
// 821.537 us; speedup vs baseline: 1.2556x; 1.2556x over previous
//
#include <hip/hip_runtime.h>
#include <hip/hip_bf16.h>

#define NC 4096
#define GG 1024
#define DM 128
#define HH 4
#define HDIM 32
#define FF 512
#define LL 2
#define NHCI 2
#define NS 8
#define LS2 (100.0f*100.0f)

typedef __bf16 bf16x8 __attribute__((ext_vector_type(8)));
typedef __bf16 bf16x4 __attribute__((ext_vector_type(4)));
typedef float  f32x4  __attribute__((ext_vector_type(4)));

// bijective XCD-chunk swizzle (m204)
__device__ __forceinline__ int xcd_swz(int orig, int nwg)
{
    int q = nwg >> 3, r = nwg & 7;
    int xcd = orig & 7, idx = orig >> 3;
    return (xcd < r ? xcd*(q+1) : r*(q+1) + (xcd-r)*q) + idx;
}

// ================= bf16 MFMA GEMM (m97 structure, fused epilogues) ==========
enum { MM_NONE=0, MM_BIAS, MM_BIAS_B16, MM_RELU_B16, MM_B16, MM_SIGSP_B16 };

template<int EM>
__launch_bounds__(256)
__global__ void mgemm_k(const __bf16* __restrict__ A, int lda,
                        const __bf16* __restrict__ BT, int ldb,
                        const float* __restrict__ bias,
                        float* __restrict__ C, __bf16* __restrict__ Cb, int ldc,
                        int M, int N, int K, float alpha,
                        const float* __restrict__ spd,
                        const int* __restrict__ flag)
{
    if (flag && *flag == 0) return;
    __shared__ __align__(16) __bf16 As[128][32];
    __shared__ __align__(16) __bf16 Bs[128][32];
    const int tid  = threadIdx.x;
    const int lane = tid & 63;
    const int wid  = tid >> 6;
    const int wm = wid >> 1, wn = wid & 1;
    const int nwg  = gridDim.x * gridDim.y;
    const int wg   = xcd_swz(blockIdx.y * gridDim.x + blockIdx.x, nwg);
    const int bm = (wg / gridDim.x) * 128, bn = (wg % gridDim.x) * 128;

    f32x4 acc[4][4];
    #pragma unroll
    for (int m=0;m<4;m++)
        #pragma unroll
        for (int n=0;n<4;n++) acc[m][n] = (f32x4){0.f,0.f,0.f,0.f};

    const int c0 = wid*64 + lane, c1 = c0 + 256;
    const __bf16* ga0 = A  + (size_t)(bm + (c0>>2))*lda + ((c0&3)<<3);
    const __bf16* ga1 = A  + (size_t)(bm + (c1>>2))*lda + ((c1&3)<<3);
    const __bf16* gb0 = BT + (size_t)(bn + (c0>>2))*ldb + ((c0&3)<<3);
    const __bf16* gb1 = BT + (size_t)(bn + (c1>>2))*ldb + ((c1&3)<<3);
    auto* lA = (__attribute__((address_space(3))) __bf16*)&As[0][0];
    auto* lB = (__attribute__((address_space(3))) __bf16*)&Bs[0][0];
    auto* lA0 = (__attribute__((address_space(3))) void*)(lA + (size_t)(wid*64)*8);
    auto* lA1 = (__attribute__((address_space(3))) void*)(lA + (size_t)(256 + wid*64)*8);
    auto* lB0 = (__attribute__((address_space(3))) void*)(lB + (size_t)(wid*64)*8);
    auto* lB1 = (__attribute__((address_space(3))) void*)(lB + (size_t)(256 + wid*64)*8);

    const int r  = lane & 15;
    const int kb = lane >> 4;
    const int arow = wm*64, brow = wn*64;

    for (int k0 = 0; k0 < K; k0 += 32) {
        __builtin_amdgcn_global_load_lds((const __attribute__((address_space(1))) void*)ga0, lA0, 16, 0, 0);
        __builtin_amdgcn_global_load_lds((const __attribute__((address_space(1))) void*)ga1, lA1, 16, 0, 0);
        __builtin_amdgcn_global_load_lds((const __attribute__((address_space(1))) void*)gb0, lB0, 16, 0, 0);
        __builtin_amdgcn_global_load_lds((const __attribute__((address_space(1))) void*)gb1, lB1, 16, 0, 0);
        ga0 += 32; ga1 += 32; gb0 += 32; gb1 += 32;
        __syncthreads();
        bf16x8 af[4], bfr[4];
        #pragma unroll
        for (int m=0;m<4;m++) af[m]  = *(const bf16x8*)&As[arow + m*16 + r][kb*8];
        #pragma unroll
        for (int n=0;n<4;n++) bfr[n] = *(const bf16x8*)&Bs[brow + n*16 + r][kb*8];
        #pragma unroll
        for (int m=0;m<4;m++)
            #pragma unroll
            for (int n=0;n<4;n++)
                acc[m][n] = __builtin_amdgcn_mfma_f32_16x16x32_bf16(af[m], bfr[n], acc[m][n], 0, 0, 0);
        __syncthreads();
    }

    const int crow = (lane >> 4) * 4;
    const int ccol = lane & 15;
    #pragma unroll
    for (int m=0;m<4;m++) {
        #pragma unroll
        for (int n=0;n<4;n++) {
            const int gn = bn + wn*64 + n*16 + ccol;
            #pragma unroll
            for (int q=0;q<4;q++) {
                const int gm = bm + wm*64 + m*16 + crow + q;
                float v = acc[m][n][q] * alpha;
                if (EM==MM_BIAS || EM==MM_BIAS_B16 || EM==MM_RELU_B16) v += bias[gn];
                if (EM==MM_RELU_B16) v = fmaxf(v, 0.f);
                if (EM==MM_SIGSP_B16) {
                    v = 1.f/(1.f + __expf(-v));
                    v *= __expf(spd[(size_t)gm*(size_t)N + gn] * (-1.f/LS2));
                }
                const size_t ci = (size_t)gm*ldc + gn;
                if (EM==MM_NONE || EM==MM_BIAS) C[ci] = v;
                else Cb[ci] = (__bf16)v;
            }
        }
    }
}

// ================= split-K MFMA GEMM: partials to P[ks][M][N] fp32 ==========
__launch_bounds__(256)
__global__ void mgemm_sk(const __bf16* __restrict__ A, int lda,
                         const __bf16* __restrict__ BT, int ldb,
                         float* __restrict__ P, int M, int N, int KC,
                         const int* __restrict__ flag)
{
    if (flag && *flag == 0) return;
    __shared__ __align__(16) __bf16 As[128][32];
    __shared__ __align__(16) __bf16 Bs[128][32];
    const int tid  = threadIdx.x;
    const int lane = tid & 63;
    const int wid  = tid >> 6;
    const int wm = wid >> 1, wn = wid & 1;
    const int nwg  = gridDim.x * gridDim.y;
    const int wg   = xcd_swz(blockIdx.y * gridDim.x + blockIdx.x, nwg);
    const int bm = (wg / gridDim.x) * 128, bn = (wg % gridDim.x) * 128;
    const size_t koff = (size_t)blockIdx.z * KC;

    f32x4 acc[4][4];
    #pragma unroll
    for (int m=0;m<4;m++)
        #pragma unroll
        for (int n=0;n<4;n++) acc[m][n] = (f32x4){0.f,0.f,0.f,0.f};

    const int c0 = wid*64 + lane, c1 = c0 + 256;
    const __bf16* ga0 = A  + (size_t)(bm + (c0>>2))*lda + koff + ((c0&3)<<3);
    const __bf16* ga1 = A  + (size_t)(bm + (c1>>2))*lda + koff + ((c1&3)<<3);
    const __bf16* gb0 = BT + (size_t)(bn + (c0>>2))*ldb + koff + ((c0&3)<<3);
    const __bf16* gb1 = BT + (size_t)(bn + (c1>>2))*ldb + koff + ((c1&3)<<3);
    auto* lA = (__attribute__((address_space(3))) __bf16*)&As[0][0];
    auto* lB = (__attribute__((address_space(3))) __bf16*)&Bs[0][0];
    auto* lA0 = (__attribute__((address_space(3))) void*)(lA + (size_t)(wid*64)*8);
    auto* lA1 = (__attribute__((address_space(3))) void*)(lA + (size_t)(256 + wid*64)*8);
    auto* lB0 = (__attribute__((address_space(3))) void*)(lB + (size_t)(wid*64)*8);
    auto* lB1 = (__attribute__((address_space(3))) void*)(lB + (size_t)(256 + wid*64)*8);

    const int r  = lane & 15;
    const int kb = lane >> 4;
    const int arow = wm*64, brow = wn*64;

    for (int k0 = 0; k0 < KC; k0 += 32) {
        __builtin_amdgcn_global_load_lds((const __attribute__((address_space(1))) void*)ga0, lA0, 16, 0, 0);
        __builtin_amdgcn_global_load_lds((const __attribute__((address_space(1))) void*)ga1, lA1, 16, 0, 0);
        __builtin_amdgcn_global_load_lds((const __attribute__((address_space(1))) void*)gb0, lB0, 16, 0, 0);
        __builtin_amdgcn_global_load_lds((const __attribute__((address_space(1))) void*)gb1, lB1, 16, 0, 0);
        ga0 += 32; ga1 += 32; gb0 += 32; gb1 += 32;
        __syncthreads();
        bf16x8 af[4], bfr[4];
        #pragma unroll
        for (int m=0;m<4;m++) af[m]  = *(const bf16x8*)&As[arow + m*16 + r][kb*8];
        #pragma unroll
        for (int n=0;n<4;n++) bfr[n] = *(const bf16x8*)&Bs[brow + n*16 + r][kb*8];
        #pragma unroll
        for (int m=0;m<4;m++)
            #pragma unroll
            for (int n=0;n<4;n++)
                acc[m][n] = __builtin_amdgcn_mfma_f32_16x16x32_bf16(af[m], bfr[n], acc[m][n], 0, 0, 0);
        __syncthreads();
    }

    float* Pz = P + (size_t)blockIdx.z * M * N;
    const int crow = (lane >> 4) * 4;
    const int ccol = lane & 15;
    #pragma unroll
    for (int m=0;m<4;m++)
        #pragma unroll
        for (int n=0;n<4;n++) {
            const int gn = bn + wn*64 + n*16 + ccol;
            #pragma unroll
            for (int q=0;q<4;q++) {
                const int gm = bm + wm*64 + m*16 + crow + q;
                Pz[(size_t)gm*N + gn] = acc[m][n][q];
            }
        }
}

// ================= split-K reduce with fused epilogues ======================
enum { R_F32=0, R_B16LD, R_ACCG, R_RELU_B16, R_BIASRES, R_TANH, R_BOTH };

template<int RE>
__launch_bounds__(256)
__global__ void redk_k(const float* __restrict__ P, int M, int N, int KS,
                       const float* __restrict__ bias,
                       const float* __restrict__ res, int ldres,
                       float* __restrict__ C, __bf16* __restrict__ Cb,
                       int ldout, int coff,
                       const int* __restrict__ flag, float alpha)
{
    if (flag && *flag == 0) return;
    int i = blockIdx.x*256 + threadIdx.x;
    int total = (M*N) >> 2;
    if (i >= total) return;
    int row = i / (N >> 2);
    int c4  = (i - row*(N >> 2)) << 2;
    f32x4 s = *(const f32x4*)(P + (size_t)row*N + c4);
    for (int ks = 1; ks < KS; ++ks)
        s += *(const f32x4*)(P + ((size_t)ks*M + row)*N + c4);
    #pragma unroll
    for (int j=0;j<4;j++) {
        int col = c4 + j;
        float v = s[j];
        if (RE==R_RELU_B16) v = fmaxf(v + bias[col], 0.f);
        if (RE==R_BIASRES)  v = v + bias[col] + res[(size_t)row*ldres + col];
        if (RE==R_TANH)     v = tanhf(v + bias[col]);
        if (RE==R_BOTH)     v = v + bias[col];
        size_t o = (size_t)row*ldout + coff + col;
        if (RE==R_F32 || RE==R_BIASRES || RE==R_TANH) C[o] = v;
        if (RE==R_BOTH) { C[o] = v; Cb[o] = (__bf16)v; }
        if (RE==R_B16LD || RE==R_RELU_B16) Cb[o] = (__bf16)v;
        if (RE==R_ACCG) C[o] += v * alpha;
    }
}

// ================= flash attention, KV-split partials =======================
// grid: (NC/64, HH, NS). Per wave: 16 q-rows, KV chunk of NC/NS.
// Writes unnormalized oacc + per-row (m, l).
__launch_bounds__(256)
__global__ void flashp_k(const __bf16* __restrict__ Q, const __bf16* __restrict__ Kb,
                         int ldqk, const __bf16* __restrict__ VT,
                         float* __restrict__ Op, float* __restrict__ mp,
                         float* __restrict__ lp)
{
    __shared__ __align__(16) __bf16 Plds[4][16][72];
    const int lane = threadIdx.x & 63, w = threadIdx.x >> 6;
    const int hd = blockIdx.y, sp = blockIdx.z;
    const int q0 = blockIdx.x * 64 + w * 16;
    const int c  = lane & 15, kb = lane >> 4;
    const float scale = 0.17677669529663687f;

    const bf16x8 aq = *(const bf16x8*)&Q[(size_t)(q0 + c)*ldqk + hd*HDIM + kb*8];
    float m[4], l[4];
    #pragma unroll
    for (int q=0;q<4;q++) { m[q] = -3.0e38f; l[q] = 0.f; }
    f32x4 oacc[2] = {(f32x4){0,0,0,0}, (f32x4){0,0,0,0}};

    const int kv0 = sp * (NC/NS), kv1 = kv0 + NC/NS;
    for (int kv = kv0; kv < kv1; kv += 64) {
        f32x4 s[4];
        #pragma unroll
        for (int n=0;n<4;n++) {
            bf16x8 bk = *(const bf16x8*)&Kb[(size_t)(kv + n*16 + c)*ldqk + hd*HDIM + kb*8];
            s[n] = __builtin_amdgcn_mfma_f32_16x16x32_bf16(aq, bk, (f32x4){0,0,0,0}, 0, 0, 0);
        }
        float f[4];
        #pragma unroll
        for (int q=0;q<4;q++) {
            float t = fmaxf(fmaxf(s[0][q], s[1][q]), fmaxf(s[2][q], s[3][q]));
            #pragma unroll
            for (int o=1;o<16;o<<=1) t = fmaxf(t, __shfl_xor(t, o));
            float nm = fmaxf(m[q], t * scale);
            f[q] = __expf(m[q] - nm);
            m[q] = nm;
        }
        float psum[4] = {0.f,0.f,0.f,0.f};
        #pragma unroll
        for (int n=0;n<4;n++) {
            #pragma unroll
            for (int q=0;q<4;q++) {
                float p = __expf(s[n][q]*scale - m[q]);
                psum[q] += p;
                Plds[w][kb*4+q][n*16+c] = (__bf16)p;
            }
        }
        #pragma unroll
        for (int q=0;q<4;q++) {
            float t = psum[q];
            #pragma unroll
            for (int o=1;o<16;o<<=1) t += __shfl_xor(t, o);
            l[q] = l[q]*f[q] + t;
            oacc[0][q] *= f[q];
            oacc[1][q] *= f[q];
        }
        #pragma unroll
        for (int ks=0;ks<2;ks++) {
            bf16x8 ap = *(const bf16x8*)&Plds[w][c][ks*32 + kb*8];
            #pragma unroll
            for (int n2=0;n2<2;n2++) {
                bf16x8 bv = *(const bf16x8*)&VT[(size_t)(hd*HDIM + n2*16 + c)*NC + kv + ks*32 + kb*8];
                oacc[n2] = __builtin_amdgcn_mfma_f32_16x16x32_bf16(ap, bv, oacc[n2], 0, 0, 0);
            }
        }
    }
    float* Oz = Op + (size_t)sp * NC * DM;
    #pragma unroll
    for (int n2=0;n2<2;n2++)
        #pragma unroll
        for (int q=0;q<4;q++)
            Oz[(size_t)(q0 + kb*4 + q)*DM + hd*HDIM + n2*16 + c] = oacc[n2][q];
    if (c == 0) {
        #pragma unroll
        for (int q=0;q<4;q++) {
            int row = q0 + kb*4 + q;
            mp[((size_t)sp*HH + hd)*NC + row] = m[q];
            lp[((size_t)sp*HH + hd)*NC + row] = l[q];
        }
    }
}

// merge NS partials -> O bf16 [NC][DM]
__launch_bounds__(256)
__global__ void flashmerge_k(const float* __restrict__ Op, const float* __restrict__ mp,
                             const float* __restrict__ lp, __bf16* __restrict__ O)
{
    int idx = blockIdx.x*256 + threadIdx.x;     // < NC*DM
    int row = idx >> 7, col = idx & 127, hd = col >> 5;
    float ms[NS];
    float M = -3.0e38f;
    #pragma unroll
    for (int s=0;s<NS;s++) {
        ms[s] = mp[((size_t)s*HH + hd)*NC + row];
        M = fmaxf(M, ms[s]);
    }
    float L = 0.f, acc = 0.f;
    #pragma unroll
    for (int s=0;s<NS;s++) {
        float w = __expf(ms[s] - M);
        L   += lp[((size_t)s*HH + hd)*NC + row] * w;
        acc += Op[(size_t)s*NC*DM + idx] * w;
    }
    O[idx] = (__bf16)(acc / L);
}

// ================= small kernels =================
__global__ void qualify2_k(const float* __restrict__ Tq, const float* __restrict__ w,
                           const float* __restrict__ b2, float* __restrict__ quality)
{
    int row = blockIdx.x, lane = threadIdx.x;
    float v = Tq[row*128 + lane] * w[lane];
    #pragma unroll
    for (int o=32;o>0;o>>=1) v += __shfl_down(v, o);
    if (lane == 0) quality[row] = v + b2[0];
}

__global__ void qw1pad_k(const float* __restrict__ W, __bf16* __restrict__ out)
{
    int idx = blockIdx.x*256 + threadIdx.x;
    int k = idx & 1023, j = idx >> 10;
    out[(size_t)j*GG + k] = (j < 64) ? (__bf16)W[(size_t)k*64 + j] : (__bf16)0.f;
}

__global__ void padb_k(const float* __restrict__ b, float* __restrict__ out)
{
    int i = threadIdx.x;
    out[i] = (i < 64) ? b[i] : 0.f;
}

__global__ void qkvpack_k(const float* __restrict__ Wq, const float* __restrict__ Wk,
                          const float* __restrict__ Wv,
                          const float* __restrict__ bq, const float* __restrict__ bk,
                          const float* __restrict__ bv,
                          __bf16* __restrict__ WT, float* __restrict__ bb)
{
    int l = blockIdx.y;
    int i = blockIdx.x*256 + threadIdx.x;
    int n = i >> 7, k = i & 127;
    const float* W = (n < 128) ? Wq : (n < 256 ? Wk : Wv);
    int nn = n & 127;
    WT[(size_t)l*384*128 + i] = (__bf16)W[(size_t)l*DM*DM + (size_t)k*DM + nn];
    if (i < 384) {
        const float* b = (i < 128) ? bq : (i < 256 ? bk : bv);
        bb[l*384 + i] = b[l*DM + (i & 127)];
    }
}

__global__ void rownorm_k(const float* __restrict__ h, float* __restrict__ sq)
{
    int row = blockIdx.x, lane = threadIdx.x;
    float x0 = h[row*DM + lane], x1 = h[row*DM + lane + 64];
    float v = x0*x0 + x1*x1;
    #pragma unroll
    for (int o=32;o>0;o>>=1) v += __shfl_down(v, o);
    if (lane == 0) sq[row] = v;
}

__global__ void add_ln_k(float* __restrict__ h, __bf16* __restrict__ hb,
                         const float* __restrict__ t,
                         const float* __restrict__ g, const float* __restrict__ b)
{
    int row = blockIdx.x, lane = threadIdx.x;
    float x0 = h[row*DM + lane]      + t[row*DM + lane];
    float x1 = h[row*DM + lane + 64] + t[row*DM + lane + 64];
    float s = x0 + x1, ss = x0*x0 + x1*x1;
    #pragma unroll
    for (int o=32;o>0;o>>=1) { s += __shfl_down(s, o); ss += __shfl_down(ss, o); }
    s = __shfl(s, 0); ss = __shfl(ss, 0);
    float mean = s * (1.f/128.f);
    float var  = ss * (1.f/128.f) - mean*mean;
    float inv  = rsqrtf(var + 1e-5f);
    float y0 = g[lane]      * (x0 - mean) * inv + b[lane];
    float y1 = g[lane + 64] * (x1 - mean) * inv + b[lane + 64];
    h[row*DM + lane]       = y0;  h[row*DM + lane + 64]  = y1;
    hb[row*DM + lane]      = (__bf16)y0;
    hb[row*DM + lane + 64] = (__bf16)y1;
}

__launch_bounds__(256)
__global__ void dist_softmax_k(const float* __restrict__ Sg, const float* __restrict__ sqv,
                               const float* __restrict__ qual, __bf16* __restrict__ P, int W)
{
    __shared__ float sm[4], sl[4];
    size_t row = blockIdx.x;
    const float* p = Sg + row * (size_t)W;
    __bf16* po = P + row * (size_t)W;
    int tid = threadIdx.x;
    float sqi = sqv[row];
    float m = -3.0e38f, l = 0.f;
    for (int j = tid; j < W; j += 256) {
        float d2 = fmaxf(sqi + sqv[j] - 2.f * p[j], 0.f);
        float lg = -sqrtf(d2) + qual[j];
        float mn = fmaxf(m, lg);
        l = l * __expf(m - mn) + __expf(lg - mn);
        m = mn;
    }
    #pragma unroll
    for (int o=32;o>0;o>>=1) {
        float m2 = __shfl_down(m, o), l2 = __shfl_down(l, o);
        float mn = fmaxf(m, m2);
        l = l * __expf(m - mn) + l2 * __expf(m2 - mn);
        m = mn;
    }
    if ((tid & 63) == 0) { sm[tid >> 6] = m; sl[tid >> 6] = l; }
    __syncthreads();
    m = sm[0]; l = sl[0];
    #pragma unroll
    for (int i=1;i<4;i++) {
        float mn = fmaxf(m, sm[i]);
        l = l * __expf(m - mn) + sl[i] * __expf(sm[i] - mn);
        m = mn;
    }
    float inv = 1.f / l;
    for (int j = tid; j < W; j += 256) {
        float d2 = fmaxf(sqi + sqv[j] - 2.f * p[j], 0.f);
        float lg = -sqrtf(d2) + qual[j];
        po[j] = (__bf16)(__expf(lg - m) * inv);
    }
}

__global__ void tconv_ld_k(const float* __restrict__ in, __bf16* __restrict__ out,
                           int R, int C, int ldout, int coff,
                           const int* __restrict__ flag)
{
    if (flag && *flag == 0) return;
    __shared__ float tile[32][33];
    int bc = blockIdx.x * 32, br = blockIdx.y * 32;
    int tx = threadIdx.x & 31, ty = threadIdx.x >> 5;
    #pragma unroll
    for (int i=0;i<4;i++)
        tile[ty + 8*i][tx] = in[(size_t)(br + ty + 8*i)*C + bc + tx];
    __syncthreads();
    #pragma unroll
    for (int i=0;i<4;i++)
        out[(size_t)(bc + ty + 8*i)*ldout + coff + br + tx] = (__bf16)tile[tx][ty + 8*i];
}

__global__ void tconv16_k(const __bf16* __restrict__ in, int ldin, int coff,
                          __bf16* __restrict__ out, int R)
{
    __shared__ __bf16 tile[32][33];
    int bc = blockIdx.x * 32, br = blockIdx.y * 32;
    int tx = threadIdx.x & 31, ty = threadIdx.x >> 5;
    #pragma unroll
    for (int i=0;i<4;i++)
        tile[ty + 8*i][tx] = in[(size_t)(br + ty + 8*i)*ldin + coff + bc + tx];
    __syncthreads();
    #pragma unroll
    for (int i=0;i<4;i++)
        out[(size_t)(bc + ty + 8*i)*R + br + tx] = tile[tx][ty + 8*i];
}

__global__ void conv_k(const float* __restrict__ in, __bf16* __restrict__ out, int n4)
{
    int i = blockIdx.x * 256 + threadIdx.x;
    if (i < n4) {
        float4 v = ((const float4*)in)[i];
        bf16x4 o = {(__bf16)v.x, (__bf16)v.y, (__bf16)v.z, (__bf16)v.w};
        ((bf16x4*)out)[i] = o;
    }
}

// ================= launchers =================
static void mg(int em, const __bf16* A, int lda, const __bf16* BT, int ldb,
               const float* bias, float* C, __bf16* Cb, int ldc,
               int M, int N, int K, float alpha,
               const float* spd, const int* flag, hipStream_t s)
{
    dim3 grid(N/128, M/128), block(256);
#define MGL(E) mgemm_k<E><<<grid,block,0,s>>>(A,lda,BT,ldb,bias,C,Cb,ldc,M,N,K,alpha,spd,flag)
    switch (em) {
        case MM_NONE:      MGL(MM_NONE);      break;
        case MM_BIAS:      MGL(MM_BIAS);      break;
        case MM_BIAS_B16:  MGL(MM_BIAS_B16);  break;
        case MM_RELU_B16:  MGL(MM_RELU_B16);  break;
        case MM_B16:       MGL(MM_B16);       break;
        case MM_SIGSP_B16: MGL(MM_SIGSP_B16); break;
    }
#undef MGL
}

static void sk(const __bf16* A, int lda, const __bf16* BT, int ldb,
               float* P, int M, int N, int K, int KS, const int* flag, hipStream_t s)
{
    dim3 grid(N/128, M/128, KS), block(256);
    mgemm_sk<<<grid, block, 0, s>>>(A, lda, BT, ldb, P, M, N, K/KS, flag);
}

static void red(int re, const float* P, int M, int N, int KS,
                const float* bias, const float* res, int ldres,
                float* C, __bf16* Cb, int ldout, int coff,
                const int* flag, float alpha, hipStream_t s)
{
    int blocks = (M*N/4 + 255) / 256;
#define RDL(E) redk_k<E><<<blocks,256,0,s>>>(P,M,N,KS,bias,res,ldres,C,Cb,ldout,coff,flag,alpha)
    switch (re) {
        case R_F32:      RDL(R_F32);      break;
        case R_B16LD:    RDL(R_B16LD);    break;
        case R_ACCG:     RDL(R_ACCG);     break;
        case R_RELU_B16: RDL(R_RELU_B16); break;
        case R_BIASRES:  RDL(R_BIASRES);  break;
        case R_TANH:     RDL(R_TANH);     break;
        case R_BOTH:     RDL(R_BOTH);     break;
    }
#undef RDL
}

static void tc(const float* in, __bf16* out, int R, int C, const int* flag, hipStream_t s)
{
    dim3 grid(C/32, R/32), block(256);
    tconv_ld_k<<<grid, block, 0, s>>>(in, out, R, C, R, 0, flag);
}

extern "C" void kernel_launch(void* const* d_in, const int* in_sizes, int n_in,
                              void* d_out, int out_size, void* d_ws, size_t ws_size,
                              hipStream_t stream)
{
    const float* raw   = (const float*)d_in[0];
    const float* spd   = (const float*)d_in[1];
    const float* dn_W1 = (const float*)d_in[2];
    const float* dn_b1 = (const float*)d_in[3];
    const float* dn_W2 = (const float*)d_in[4];
    const float* dn_b2 = (const float*)d_in[5];
    const float* q_W1  = (const float*)d_in[6];
    const float* q_b1  = (const float*)d_in[7];
    const float* q_W2  = (const float*)d_in[8];
    const float* q_b2  = (const float*)d_in[9];
    const float* e_Win = (const float*)d_in[10];
    const float* e_bin = (const float*)d_in[11];
    const float* Wq    = (const float*)d_in[12];
    const float* Wk    = (const float*)d_in[13];
    const float* Wv    = (const float*)d_in[14];
    const float* Wo    = (const float*)d_in[15];
    const float* bq    = (const float*)d_in[16];
    const float* bk    = (const float*)d_in[17];
    const float* bv    = (const float*)d_in[18];
    const float* bo    = (const float*)d_in[19];
    const float* ln1_g = (const float*)d_in[20];
    const float* ln1_b = (const float*)d_in[21];
    const float* ln2_g = (const float*)d_in[22];
    const float* ln2_b = (const float*)d_in[23];
    const float* f_W1  = (const float*)d_in[24];
    const float* f_b1  = (const float*)d_in[25];
    const float* f_W2  = (const float*)d_in[26];
    const float* f_b2  = (const float*)d_in[27];
    const float* ci_T  = (const float*)d_in[28];
    const float* ci_G  = (const float*)d_in[29];
    const int*   interact = (const int*)d_in[30];
    (void)in_sizes; (void)n_in; (void)ws_size; (void)out_size;

    float* out = (float*)d_out;
    float* ws = (float*)d_ws;
    size_t off = 0;
    auto af32 = [&](size_t n) { float* p = ws + off; off += n; return p; };
    auto ab16 = [&](size_t n) { __bf16* p = (__bf16*)(ws + off); off += (n + 1) / 2; return p; };

    float*  S        = af32((size_t)NC * NC);   // gram / split-K partials / flash partials
    float*  denoised = af32((size_t)NC * GG);
    __bf16* simB     = ab16((size_t)NC * NC);
    __bf16* ciS      = ab16((size_t)NC * NC);
    __bf16* T1b      = ab16((size_t)NC * FF);
    float*  Tq       = af32((size_t)NC * 128);
    float*  quality  = af32(NC);
    float*  h        = af32((size_t)NC * DM);
    __bf16* hb       = ab16((size_t)NC * DM);
    __bf16* qkvB     = ab16((size_t)NC * 384);
    __bf16* vbT      = ab16((size_t)DM * NC);
    __bf16* obB      = ab16((size_t)NC * DM);
    float*  t2       = af32((size_t)NC * DM);
    __bf16* rawB     = ab16((size_t)NC * GG);
    __bf16* denT     = ab16((size_t)GG * NC);
    __bf16* smoT     = ab16((size_t)GG * NC);
    __bf16* Ubig     = ab16((size_t)NC * 2*GG);
    __bf16* TembB    = ab16((size_t)NC * DM);
    float*  sqbuf    = af32(NC);
    __bf16* dnW1T    = ab16((size_t)FF * GG);
    __bf16* dnW2T    = ab16((size_t)GG * FF);
    __bf16* eWinT    = ab16((size_t)DM * GG);
    __bf16* qW1pT    = ab16((size_t)128 * GG);
    float*  qb1p     = af32(128);
    __bf16* Wqkv     = ab16((size_t)LL * 384 * DM);
    float*  bqkv     = af32((size_t)LL * 384);
    __bf16* WoT      = ab16((size_t)LL * DM * DM);
    __bf16* fW1T     = ab16((size_t)LL * FF * DM);
    __bf16* fW2T     = ab16((size_t)LL * DM * FF);
    __bf16* ciTT     = ab16((size_t)NHCI * DM * DM);
    __bf16* ciGbigT  = ab16((size_t)GG * 2*GG);

    // flash partial buffers live inside S (dead during transformer phase)
    float* Opart = S;                                   // NS*NC*DM fp32
    float* mpart = S + (size_t)NS*NC*DM;                // NS*HH*NC
    float* lpart = mpart + (size_t)NS*HH*NC;            // NS*HH*NC

    // ---- packs / conversions ----
    tc(dn_W1, dnW1T, GG, FF, nullptr, stream);
    tc(dn_W2, dnW2T, FF, GG, nullptr, stream);
    tc(e_Win, eWinT, GG, DM, nullptr, stream);
    qw1pad_k<<<(128*GG)/256, 256, 0, stream>>>(q_W1, qW1pT);
    padb_k<<<1, 128, 0, stream>>>(q_b1, qb1p);
    qkvpack_k<<<dim3(192, LL), 256, 0, stream>>>(Wq, Wk, Wv, bq, bk, bv, Wqkv, bqkv);
    for (int l = 0; l < LL; ++l) {
        tc(Wo + (size_t)l*DM*DM, WoT + (size_t)l*DM*DM, DM, DM, nullptr, stream);
        tc(f_W1 + (size_t)l*DM*FF, fW1T + (size_t)l*FF*DM, DM, FF, nullptr, stream);
        tc(f_W2 + (size_t)l*FF*DM, fW2T + (size_t)l*DM*FF, FF, DM, nullptr, stream);
    }
    conv_k<<<(NC*GG/4 + 255)/256, 256, 0, stream>>>(raw, rawB, NC*GG/4);

    // ---- CellDenoise (split-K) ----
    sk(rawB, GG, dnW1T, GG, S, NC, FF, GG, 8, nullptr, stream);
    red(R_RELU_B16, S, NC, FF, 8, dn_b1, nullptr, 0, nullptr, T1b, FF, 0, nullptr, 1.f, stream);
    sk(T1b, FF, dnW2T, FF, S, NC, GG, FF, 4, nullptr, stream);
    red(R_BIASRES, S, NC, GG, 4, dn_b2, raw, GG, denoised, nullptr, GG, 0, nullptr, 1.f, stream);
    // ---- CellQualify (split-K, padded N=128) ----
    sk(rawB, GG, qW1pT, GG, S, NC, 128, GG, 8, nullptr, stream);
    red(R_TANH, S, NC, 128, 8, qb1p, nullptr, 0, Tq, nullptr, 128, 0, nullptr, 1.f, stream);
    qualify2_k<<<NC, 64, 0, stream>>>(Tq, q_W2, q_b2, quality);
    // ---- CellEmbed input proj (split-K) ----
    sk(rawB, GG, eWinT, GG, S, NC, 128, GG, 8, nullptr, stream);
    red(R_BOTH, S, NC, 128, 8, e_bin, nullptr, 0, h, hb, 128, 0, nullptr, 1.f, stream);
    // ---- Transformer layers ----
    for (int l = 0; l < LL; ++l) {
        mg(MM_BIAS_B16, hb, DM, Wqkv + (size_t)l*384*DM, DM, bqkv + l*384,
           nullptr, qkvB, 384, NC, 384, DM, 1.f, nullptr, nullptr, stream);
        tconv16_k<<<dim3(DM/32, NC/32), 256, 0, stream>>>(qkvB, 384, 256, vbT, NC);
        flashp_k<<<dim3(NC/64, HH, NS), 256, 0, stream>>>(qkvB, qkvB + 128, 384, vbT,
                                                          Opart, mpart, lpart);
        flashmerge_k<<<(NC*DM)/256, 256, 0, stream>>>(Opart, mpart, lpart, obB);
        mg(MM_BIAS, obB, DM, WoT + (size_t)l*DM*DM, DM, bo + l*DM,
           t2, nullptr, DM, NC, DM, DM, 1.f, nullptr, nullptr, stream);
        add_ln_k<<<NC, 64, 0, stream>>>(h, hb, t2, ln1_g + l*DM, ln1_b + l*DM);
        mg(MM_RELU_B16, hb, DM, fW1T + (size_t)l*FF*DM, DM, f_b1 + l*FF,
           nullptr, T1b, FF, NC, FF, DM, 1.f, nullptr, nullptr, stream);
        mg(MM_BIAS, T1b, FF, fW2T + (size_t)l*DM*FF, FF, f_b2 + l*DM,
           t2, nullptr, DM, NC, DM, FF, 1.f, nullptr, nullptr, stream);
        add_ln_k<<<NC, 64, 0, stream>>>(h, hb, t2, ln2_g + l*DM, ln2_b + l*DM);
    }
    // ---- CellSmooth ----
    rownorm_k<<<NC, 64, 0, stream>>>(h, sqbuf);
    mg(MM_NONE, hb, DM, hb, DM, nullptr, S, nullptr, NC, NC, NC, DM, 1.f, nullptr, nullptr, stream);
    dist_softmax_k<<<NC, 256, 0, stream>>>(S, sqbuf, quality, simB, NC);
    tc(denoised, denT, NC, GG, nullptr, stream);
    sk(simB, NC, denT, NC, S, NC, GG, NC, 4, nullptr, stream);
    red(R_F32, S, NC, GG, 4, nullptr, nullptr, 0, out, nullptr, GG, 0, nullptr, 1.f, stream);
    // ---- CellInteract (gated on *interact) ----
    tc(out, smoT, NC, GG, interact, stream);
    for (int hh = 0; hh < NHCI; ++hh) {
        tc(ci_T + (size_t)hh*DM*DM, ciTT + (size_t)hh*DM*DM, DM, DM, interact, stream);
        dim3 gg(GG/32, GG/32);
        tconv_ld_k<<<gg, 256, 0, stream>>>(ci_G + (size_t)hh*GG*GG, ciGbigT, GG, GG,
                                           2*GG, hh*GG, interact);
    }
    for (int hh = 0; hh < NHCI; ++hh) {
        mg(MM_B16, hb, DM, ciTT + (size_t)hh*DM*DM, DM, nullptr,
           nullptr, TembB, DM, NC, DM, DM, 1.f, nullptr, interact, stream);
        mg(MM_SIGSP_B16, TembB, DM, hb, DM, nullptr,
           nullptr, ciS, NC, NC, NC, DM, 1.f, spd, interact, stream);
        sk(ciS, NC, smoT, NC, S, NC, GG, NC, 4, interact, stream);
        red(R_B16LD, S, NC, GG, 4, nullptr, nullptr, 0, nullptr, Ubig, 2*GG, hh*GG,
            interact, 1.f, stream);
    }
    sk(Ubig, 2*GG, ciGbigT, 2*GG, S, NC, GG, 2*GG, 4, interact, stream);
    red(R_ACCG, S, NC, GG, 4, nullptr, nullptr, 0, out, nullptr, GG, 0,
        interact, 1.0f/1024.f, stream);
}

// Round 6
// 769.285 us; speedup vs baseline: 1.3409x; 1.0679x over previous
//
#include <hip/hip_runtime.h>
#include <hip/hip_bf16.h>

#define NC 4096
#define GG 1024
#define DM 128
#define HH 4
#define HDIM 32
#define FF 512
#define LL 2
#define NHCI 2
#define NS 8
#define LS2 (100.0f*100.0f)

typedef __bf16 bf16x8 __attribute__((ext_vector_type(8)));
typedef __bf16 bf16x4 __attribute__((ext_vector_type(4)));
typedef float  f32x4  __attribute__((ext_vector_type(4)));

// bijective XCD-chunk swizzle (m204)
__device__ __forceinline__ int xcd_swz(int orig, int nwg)
{
    int q = nwg >> 3, r = nwg & 7;
    int xcd = orig & 7, idx = orig >> 3;
    return (xcd < r ? xcd*(q+1) : r*(q+1) + (xcd-r)*q) + idx;
}

// ================= bf16 MFMA GEMM (m97 structure, fused epilogues) ==========
enum { MM_NONE=0, MM_BIAS, MM_BIAS_B16, MM_RELU_B16, MM_B16, MM_SIGSP_B16 };

template<int EM>
__launch_bounds__(256)
__global__ void mgemm_k(const __bf16* __restrict__ A, int lda,
                        const __bf16* __restrict__ BT, int ldb,
                        const float* __restrict__ bias,
                        float* __restrict__ C, __bf16* __restrict__ Cb, int ldc,
                        int M, int N, int K, float alpha,
                        const __bf16* __restrict__ sp16,
                        const int* __restrict__ flag)
{
    if (flag && *flag == 0) return;
    __shared__ __align__(16) __bf16 As[128][32];
    __shared__ __align__(16) __bf16 Bs[128][32];
    const int tid  = threadIdx.x;
    const int lane = tid & 63;
    const int wid  = tid >> 6;
    const int wm = wid >> 1, wn = wid & 1;
    const int nwg  = gridDim.x * gridDim.y;
    const int wg   = xcd_swz(blockIdx.y * gridDim.x + blockIdx.x, nwg);
    const int bm = (wg / gridDim.x) * 128, bn = (wg % gridDim.x) * 128;

    f32x4 acc[4][4];
    #pragma unroll
    for (int m=0;m<4;m++)
        #pragma unroll
        for (int n=0;n<4;n++) acc[m][n] = (f32x4){0.f,0.f,0.f,0.f};

    const int c0 = wid*64 + lane, c1 = c0 + 256;
    const __bf16* ga0 = A  + (size_t)(bm + (c0>>2))*lda + ((c0&3)<<3);
    const __bf16* ga1 = A  + (size_t)(bm + (c1>>2))*lda + ((c1&3)<<3);
    const __bf16* gb0 = BT + (size_t)(bn + (c0>>2))*ldb + ((c0&3)<<3);
    const __bf16* gb1 = BT + (size_t)(bn + (c1>>2))*ldb + ((c1&3)<<3);
    auto* lA = (__attribute__((address_space(3))) __bf16*)&As[0][0];
    auto* lB = (__attribute__((address_space(3))) __bf16*)&Bs[0][0];
    auto* lA0 = (__attribute__((address_space(3))) void*)(lA + (size_t)(wid*64)*8);
    auto* lA1 = (__attribute__((address_space(3))) void*)(lA + (size_t)(256 + wid*64)*8);
    auto* lB0 = (__attribute__((address_space(3))) void*)(lB + (size_t)(wid*64)*8);
    auto* lB1 = (__attribute__((address_space(3))) void*)(lB + (size_t)(256 + wid*64)*8);

    const int r  = lane & 15;
    const int kb = lane >> 4;
    const int arow = wm*64, brow = wn*64;

    for (int k0 = 0; k0 < K; k0 += 32) {
        __builtin_amdgcn_global_load_lds((const __attribute__((address_space(1))) void*)ga0, lA0, 16, 0, 0);
        __builtin_amdgcn_global_load_lds((const __attribute__((address_space(1))) void*)ga1, lA1, 16, 0, 0);
        __builtin_amdgcn_global_load_lds((const __attribute__((address_space(1))) void*)gb0, lB0, 16, 0, 0);
        __builtin_amdgcn_global_load_lds((const __attribute__((address_space(1))) void*)gb1, lB1, 16, 0, 0);
        ga0 += 32; ga1 += 32; gb0 += 32; gb1 += 32;
        __syncthreads();
        bf16x8 af[4], bfr[4];
        #pragma unroll
        for (int m=0;m<4;m++) af[m]  = *(const bf16x8*)&As[arow + m*16 + r][kb*8];
        #pragma unroll
        for (int n=0;n<4;n++) bfr[n] = *(const bf16x8*)&Bs[brow + n*16 + r][kb*8];
        #pragma unroll
        for (int m=0;m<4;m++)
            #pragma unroll
            for (int n=0;n<4;n++)
                acc[m][n] = __builtin_amdgcn_mfma_f32_16x16x32_bf16(af[m], bfr[n], acc[m][n], 0, 0, 0);
        __syncthreads();
    }

    const int crow = (lane >> 4) * 4;
    const int ccol = lane & 15;
    #pragma unroll
    for (int m=0;m<4;m++) {
        #pragma unroll
        for (int n=0;n<4;n++) {
            const int gn = bn + wn*64 + n*16 + ccol;
            #pragma unroll
            for (int q=0;q<4;q++) {
                const int gm = bm + wm*64 + m*16 + crow + q;
                float v = acc[m][n][q] * alpha;
                if (EM==MM_BIAS || EM==MM_BIAS_B16 || EM==MM_RELU_B16) v += bias[gn];
                if (EM==MM_RELU_B16) v = fmaxf(v, 0.f);
                if (EM==MM_SIGSP_B16) {
                    v = 1.f/(1.f + __expf(-v));
                    v *= (float)sp16[(size_t)gm*(size_t)N + gn];
                }
                const size_t ci = (size_t)gm*ldc + gn;
                if (EM==MM_NONE || EM==MM_BIAS) C[ci] = v;
                else Cb[ci] = (__bf16)v;
            }
        }
    }
}

// ================= split-K MFMA GEMM: partials to P[ks][M][N] fp32 ==========
__launch_bounds__(256)
__global__ void mgemm_sk(const __bf16* __restrict__ A, int lda,
                         const __bf16* __restrict__ BT, int ldb,
                         float* __restrict__ P, int M, int N, int KC,
                         const int* __restrict__ flag)
{
    if (flag && *flag == 0) return;
    __shared__ __align__(16) __bf16 As[128][32];
    __shared__ __align__(16) __bf16 Bs[128][32];
    const int tid  = threadIdx.x;
    const int lane = tid & 63;
    const int wid  = tid >> 6;
    const int wm = wid >> 1, wn = wid & 1;
    const int nwg  = gridDim.x * gridDim.y;
    const int wg   = xcd_swz(blockIdx.y * gridDim.x + blockIdx.x, nwg);
    const int bm = (wg / gridDim.x) * 128, bn = (wg % gridDim.x) * 128;
    const size_t koff = (size_t)blockIdx.z * KC;

    f32x4 acc[4][4];
    #pragma unroll
    for (int m=0;m<4;m++)
        #pragma unroll
        for (int n=0;n<4;n++) acc[m][n] = (f32x4){0.f,0.f,0.f,0.f};

    const int c0 = wid*64 + lane, c1 = c0 + 256;
    const __bf16* ga0 = A  + (size_t)(bm + (c0>>2))*lda + koff + ((c0&3)<<3);
    const __bf16* ga1 = A  + (size_t)(bm + (c1>>2))*lda + koff + ((c1&3)<<3);
    const __bf16* gb0 = BT + (size_t)(bn + (c0>>2))*ldb + koff + ((c0&3)<<3);
    const __bf16* gb1 = BT + (size_t)(bn + (c1>>2))*ldb + koff + ((c1&3)<<3);
    auto* lA = (__attribute__((address_space(3))) __bf16*)&As[0][0];
    auto* lB = (__attribute__((address_space(3))) __bf16*)&Bs[0][0];
    auto* lA0 = (__attribute__((address_space(3))) void*)(lA + (size_t)(wid*64)*8);
    auto* lA1 = (__attribute__((address_space(3))) void*)(lA + (size_t)(256 + wid*64)*8);
    auto* lB0 = (__attribute__((address_space(3))) void*)(lB + (size_t)(wid*64)*8);
    auto* lB1 = (__attribute__((address_space(3))) void*)(lB + (size_t)(256 + wid*64)*8);

    const int r  = lane & 15;
    const int kb = lane >> 4;
    const int arow = wm*64, brow = wn*64;

    for (int k0 = 0; k0 < KC; k0 += 32) {
        __builtin_amdgcn_global_load_lds((const __attribute__((address_space(1))) void*)ga0, lA0, 16, 0, 0);
        __builtin_amdgcn_global_load_lds((const __attribute__((address_space(1))) void*)ga1, lA1, 16, 0, 0);
        __builtin_amdgcn_global_load_lds((const __attribute__((address_space(1))) void*)gb0, lB0, 16, 0, 0);
        __builtin_amdgcn_global_load_lds((const __attribute__((address_space(1))) void*)gb1, lB1, 16, 0, 0);
        ga0 += 32; ga1 += 32; gb0 += 32; gb1 += 32;
        __syncthreads();
        bf16x8 af[4], bfr[4];
        #pragma unroll
        for (int m=0;m<4;m++) af[m]  = *(const bf16x8*)&As[arow + m*16 + r][kb*8];
        #pragma unroll
        for (int n=0;n<4;n++) bfr[n] = *(const bf16x8*)&Bs[brow + n*16 + r][kb*8];
        #pragma unroll
        for (int m=0;m<4;m++)
            #pragma unroll
            for (int n=0;n<4;n++)
                acc[m][n] = __builtin_amdgcn_mfma_f32_16x16x32_bf16(af[m], bfr[n], acc[m][n], 0, 0, 0);
        __syncthreads();
    }

    float* Pz = P + (size_t)blockIdx.z * M * N;
    const int crow = (lane >> 4) * 4;
    const int ccol = lane & 15;
    #pragma unroll
    for (int m=0;m<4;m++)
        #pragma unroll
        for (int n=0;n<4;n++) {
            const int gn = bn + wn*64 + n*16 + ccol;
            #pragma unroll
            for (int q=0;q<4;q++) {
                const int gm = bm + wm*64 + m*16 + crow + q;
                Pz[(size_t)gm*N + gn] = acc[m][n][q];
            }
        }
}

// ================= split-K reduce with fused epilogues ======================
enum { R_F32=0, R_B16LD, R_ACCG, R_RELU_B16, R_BIASRES, R_TANH, R_BOTH, R_RS };

template<int RE>
__launch_bounds__(256)
__global__ void redk_k(const float* __restrict__ P, int M, int N, int KS,
                       const float* __restrict__ bias,
                       const float* __restrict__ res, int ldres,
                       float* __restrict__ C, __bf16* __restrict__ Cb,
                       int ldout, int coff,
                       const int* __restrict__ flag, float alpha)
{
    if (flag && *flag == 0) return;
    int i = blockIdx.x*256 + threadIdx.x;
    int total = (M*N) >> 2;
    if (i >= total) return;
    int row = i / (N >> 2);
    int c4  = (i - row*(N >> 2)) << 2;
    f32x4 s = *(const f32x4*)(P + (size_t)row*N + c4);
    for (int ks = 1; ks < KS; ++ks)
        s += *(const f32x4*)(P + ((size_t)ks*M + row)*N + c4);
    #pragma unroll
    for (int j=0;j<4;j++) {
        int col = c4 + j;
        float v = s[j];
        if (RE==R_RELU_B16) v = fmaxf(v + bias[col], 0.f);
        if (RE==R_BIASRES)  v = v + bias[col] + res[(size_t)row*ldres + col];
        if (RE==R_TANH)     v = tanhf(v + bias[col]);
        if (RE==R_BOTH)     v = v + bias[col];
        if (RE==R_RS)       v = v * res[row];      // res = per-row scale
        size_t o = (size_t)row*ldout + coff + col;
        if (RE==R_F32 || RE==R_BIASRES || RE==R_TANH || RE==R_RS) C[o] = v;
        if (RE==R_BOTH) { C[o] = v; Cb[o] = (__bf16)v; }
        if (RE==R_B16LD || RE==R_RELU_B16) Cb[o] = (__bf16)v;
        if (RE==R_ACCG) C[o] += v * alpha;
    }
}

// ================= flash attention, KV-split partials, no-max softmax =======
// Scores are structurally bounded (|s*scale| << 80) so exp(s) cannot overflow;
// softmax shift-invariance makes this exact. Row-sum l comes from an extra
// MFMA against a ones B-fragment (matrix pipe) -- zero cross-lane shuffles.
__launch_bounds__(256)
__global__ void flashp_k(const __bf16* __restrict__ Q, const __bf16* __restrict__ Kb,
                         int ldqk, const __bf16* __restrict__ VT,
                         float* __restrict__ Op, float* __restrict__ lp)
{
    __shared__ __align__(16) __bf16 Plds[4][16][72];
    const int lane = threadIdx.x & 63, w = threadIdx.x >> 6;
    const int hd = blockIdx.y, sp = blockIdx.z;
    const int q0 = blockIdx.x * 64 + w * 16;
    const int c  = lane & 15, kb = lane >> 4;
    const float scale = 0.17677669529663687f;

    const bf16x8 aq = *(const bf16x8*)&Q[(size_t)(q0 + c)*ldqk + hd*HDIM + kb*8];
    bf16x8 ones;
    #pragma unroll
    for (int j=0;j<8;j++) ones[j] = (__bf16)1.0f;

    f32x4 oacc[2] = {(f32x4){0,0,0,0}, (f32x4){0,0,0,0}};
    f32x4 lacc = (f32x4){0,0,0,0};

    const int kv0 = sp * (NC/NS), kv1 = kv0 + NC/NS;
    for (int kv = kv0; kv < kv1; kv += 64) {
        f32x4 s[4];
        #pragma unroll
        for (int n=0;n<4;n++) {
            bf16x8 bk = *(const bf16x8*)&Kb[(size_t)(kv + n*16 + c)*ldqk + hd*HDIM + kb*8];
            s[n] = __builtin_amdgcn_mfma_f32_16x16x32_bf16(aq, bk, (f32x4){0,0,0,0}, 0, 0, 0);
        }
        #pragma unroll
        for (int n=0;n<4;n++)
            #pragma unroll
            for (int q=0;q<4;q++)
                Plds[w][kb*4+q][n*16+c] = (__bf16)__expf(s[n][q]*scale);
        #pragma unroll
        for (int ks=0;ks<2;ks++) {
            bf16x8 ap = *(const bf16x8*)&Plds[w][c][ks*32 + kb*8];
            #pragma unroll
            for (int n2=0;n2<2;n2++) {
                bf16x8 bv = *(const bf16x8*)&VT[(size_t)(hd*HDIM + n2*16 + c)*NC + kv + ks*32 + kb*8];
                oacc[n2] = __builtin_amdgcn_mfma_f32_16x16x32_bf16(ap, bv, oacc[n2], 0, 0, 0);
            }
            lacc = __builtin_amdgcn_mfma_f32_16x16x32_bf16(ap, ones, lacc, 0, 0, 0);
        }
    }
    float* Oz = Op + (size_t)sp * NC * DM;
    #pragma unroll
    for (int n2=0;n2<2;n2++)
        #pragma unroll
        for (int q=0;q<4;q++)
            Oz[(size_t)(q0 + kb*4 + q)*DM + hd*HDIM + n2*16 + c] = oacc[n2][q];
    if (c == 0) {
        #pragma unroll
        for (int q=0;q<4;q++)
            lp[((size_t)sp*HH + hd)*NC + q0 + kb*4 + q] = lacc[q];
    }
}

// merge NS partials -> O bf16 [NC][DM] (plain sums, no max)
__launch_bounds__(256)
__global__ void flashmerge_k(const float* __restrict__ Op, const float* __restrict__ lp,
                             __bf16* __restrict__ O)
{
    int idx = blockIdx.x*256 + threadIdx.x;     // < NC*DM
    int row = idx >> 7, col = idx & 127, hd = col >> 5;
    float L = 0.f, acc = 0.f;
    #pragma unroll
    for (int s=0;s<NS;s++) {
        L   += lp[((size_t)s*HH + hd)*NC + row];
        acc += Op[(size_t)s*NC*DM + idx];
    }
    O[idx] = (__bf16)(acc / L);
}

// ================= small kernels =================
__global__ void qualify2_k(const float* __restrict__ Tq, const float* __restrict__ w,
                           const float* __restrict__ b2, float* __restrict__ quality)
{
    int row = blockIdx.x, lane = threadIdx.x;
    float v = Tq[row*128 + lane] * w[lane];
    #pragma unroll
    for (int o=32;o>0;o>>=1) v += __shfl_down(v, o);
    if (lane == 0) quality[row] = v + b2[0];
}

__global__ void qw1pad_k(const float* __restrict__ W, __bf16* __restrict__ out)
{
    int idx = blockIdx.x*256 + threadIdx.x;
    int k = idx & 1023, j = idx >> 10;
    out[(size_t)j*GG + k] = (j < 64) ? (__bf16)W[(size_t)k*64 + j] : (__bf16)0.f;
}

__global__ void padb_k(const float* __restrict__ b, float* __restrict__ out)
{
    int i = threadIdx.x;
    out[i] = (i < 64) ? b[i] : 0.f;
}

__global__ void qkvpack_k(const float* __restrict__ Wq, const float* __restrict__ Wk,
                          const float* __restrict__ Wv,
                          const float* __restrict__ bq, const float* __restrict__ bk,
                          const float* __restrict__ bv,
                          __bf16* __restrict__ WT, float* __restrict__ bb)
{
    int l = blockIdx.y;
    int i = blockIdx.x*256 + threadIdx.x;
    int n = i >> 7, k = i & 127;
    const float* W = (n < 128) ? Wq : (n < 256 ? Wk : Wv);
    int nn = n & 127;
    WT[(size_t)l*384*128 + i] = (__bf16)W[(size_t)l*DM*DM + (size_t)k*DM + nn];
    if (i < 384) {
        const float* b = (i < 128) ? bq : (i < 256 ? bk : bv);
        bb[l*384 + i] = b[l*DM + (i & 127)];
    }
}

__global__ void rownorm_k(const float* __restrict__ h, float* __restrict__ sq)
{
    int row = blockIdx.x, lane = threadIdx.x;
    float x0 = h[row*DM + lane], x1 = h[row*DM + lane + 64];
    float v = x0*x0 + x1*x1;
    #pragma unroll
    for (int o=32;o>0;o>>=1) v += __shfl_down(v, o);
    if (lane == 0) sq[row] = v;
}

__global__ void add_ln_k(float* __restrict__ h, __bf16* __restrict__ hb,
                         const float* __restrict__ t,
                         const float* __restrict__ g, const float* __restrict__ b)
{
    int row = blockIdx.x, lane = threadIdx.x;
    float x0 = h[row*DM + lane]      + t[row*DM + lane];
    float x1 = h[row*DM + lane + 64] + t[row*DM + lane + 64];
    float s = x0 + x1, ss = x0*x0 + x1*x1;
    #pragma unroll
    for (int o=32;o>0;o>>=1) { s += __shfl_down(s, o); ss += __shfl_down(ss, o); }
    s = __shfl(s, 0); ss = __shfl(ss, 0);
    float mean = s * (1.f/128.f);
    float var  = ss * (1.f/128.f) - mean*mean;
    float inv  = rsqrtf(var + 1e-5f);
    float y0 = g[lane]      * (x0 - mean) * inv + b[lane];
    float y1 = g[lane + 64] * (x1 - mean) * inv + b[lane + 64];
    h[row*DM + lane]       = y0;  h[row*DM + lane + 64]  = y1;
    hb[row*DM + lane]      = (__bf16)y0;
    hb[row*DM + lane + 64] = (__bf16)y1;
}

// single-pass: write UNNORMALIZED p = exp(qual[j]-dist) bf16 + rowinv = 1/sum.
// logits <= max(quality) (~3), so exp is bounded; normalization folded into
// the downstream split-K reduce (R_RS).
__launch_bounds__(256)
__global__ void dist_softmax_k(const float* __restrict__ Sg, const float* __restrict__ sqv,
                               const float* __restrict__ qual, __bf16* __restrict__ P,
                               float* __restrict__ rinv, int W)
{
    __shared__ float sl[4];
    size_t row = blockIdx.x;
    const float* p = Sg + row * (size_t)W;
    __bf16* po = P + row * (size_t)W;
    int tid = threadIdx.x;
    float sqi = sqv[row];
    float sum = 0.f;
    for (int j = tid; j < W; j += 256) {
        float d2 = fmaxf(sqi + sqv[j] - 2.f * p[j], 0.f);
        float e = __expf(qual[j] - sqrtf(d2));
        po[j] = (__bf16)e;
        sum += e;
    }
    #pragma unroll
    for (int o=32;o>0;o>>=1) sum += __shfl_down(sum, o);
    if ((tid & 63) == 0) sl[tid >> 6] = sum;
    __syncthreads();
    if (tid == 0) rinv[row] = 1.f / (sl[0] + sl[1] + sl[2] + sl[3]);
}

// spatial = exp(-spd/LS2) as bf16, once (shared by both CI heads)
__global__ void spconv_k(const float* __restrict__ spd, __bf16* __restrict__ spB,
                         const int* __restrict__ flag)
{
    if (flag && *flag == 0) return;
    int i = blockIdx.x*256 + threadIdx.x;   // < NC*NC/4
    float4 v = ((const float4*)spd)[i];
    bf16x4 o = {(__bf16)__expf(v.x * (-1.f/LS2)), (__bf16)__expf(v.y * (-1.f/LS2)),
                (__bf16)__expf(v.z * (-1.f/LS2)), (__bf16)__expf(v.w * (-1.f/LS2))};
    ((bf16x4*)spB)[i] = o;
}

__global__ void tconv_ld_k(const float* __restrict__ in, __bf16* __restrict__ out,
                           int R, int C, int ldout, int coff,
                           const int* __restrict__ flag)
{
    if (flag && *flag == 0) return;
    __shared__ float tile[32][33];
    int bc = blockIdx.x * 32, br = blockIdx.y * 32;
    int tx = threadIdx.x & 31, ty = threadIdx.x >> 5;
    #pragma unroll
    for (int i=0;i<4;i++)
        tile[ty + 8*i][tx] = in[(size_t)(br + ty + 8*i)*C + bc + tx];
    __syncthreads();
    #pragma unroll
    for (int i=0;i<4;i++)
        out[(size_t)(bc + ty + 8*i)*ldout + coff + br + tx] = (__bf16)tile[tx][ty + 8*i];
}

__global__ void tconv16_k(const __bf16* __restrict__ in, int ldin, int coff,
                          __bf16* __restrict__ out, int R)
{
    __shared__ __bf16 tile[32][33];
    int bc = blockIdx.x * 32, br = blockIdx.y * 32;
    int tx = threadIdx.x & 31, ty = threadIdx.x >> 5;
    #pragma unroll
    for (int i=0;i<4;i++)
        tile[ty + 8*i][tx] = in[(size_t)(br + ty + 8*i)*ldin + coff + bc + tx];
    __syncthreads();
    #pragma unroll
    for (int i=0;i<4;i++)
        out[(size_t)(bc + ty + 8*i)*R + br + tx] = tile[tx][ty + 8*i];
}

__global__ void conv_k(const float* __restrict__ in, __bf16* __restrict__ out, int n4)
{
    int i = blockIdx.x * 256 + threadIdx.x;
    if (i < n4) {
        float4 v = ((const float4*)in)[i];
        bf16x4 o = {(__bf16)v.x, (__bf16)v.y, (__bf16)v.z, (__bf16)v.w};
        ((bf16x4*)out)[i] = o;
    }
}

// ================= launchers =================
static void mg(int em, const __bf16* A, int lda, const __bf16* BT, int ldb,
               const float* bias, float* C, __bf16* Cb, int ldc,
               int M, int N, int K, float alpha,
               const __bf16* sp16, const int* flag, hipStream_t s)
{
    dim3 grid(N/128, M/128), block(256);
#define MGL(E) mgemm_k<E><<<grid,block,0,s>>>(A,lda,BT,ldb,bias,C,Cb,ldc,M,N,K,alpha,sp16,flag)
    switch (em) {
        case MM_NONE:      MGL(MM_NONE);      break;
        case MM_BIAS:      MGL(MM_BIAS);      break;
        case MM_BIAS_B16:  MGL(MM_BIAS_B16);  break;
        case MM_RELU_B16:  MGL(MM_RELU_B16);  break;
        case MM_B16:       MGL(MM_B16);       break;
        case MM_SIGSP_B16: MGL(MM_SIGSP_B16); break;
    }
#undef MGL
}

static void sk(const __bf16* A, int lda, const __bf16* BT, int ldb,
               float* P, int M, int N, int K, int KS, const int* flag, hipStream_t s)
{
    dim3 grid(N/128, M/128, KS), block(256);
    mgemm_sk<<<grid, block, 0, s>>>(A, lda, BT, ldb, P, M, N, K/KS, flag);
}

static void red(int re, const float* P, int M, int N, int KS,
                const float* bias, const float* res, int ldres,
                float* C, __bf16* Cb, int ldout, int coff,
                const int* flag, float alpha, hipStream_t s)
{
    int blocks = (M*N/4 + 255) / 256;
#define RDL(E) redk_k<E><<<blocks,256,0,s>>>(P,M,N,KS,bias,res,ldres,C,Cb,ldout,coff,flag,alpha)
    switch (re) {
        case R_F32:      RDL(R_F32);      break;
        case R_B16LD:    RDL(R_B16LD);    break;
        case R_ACCG:     RDL(R_ACCG);     break;
        case R_RELU_B16: RDL(R_RELU_B16); break;
        case R_BIASRES:  RDL(R_BIASRES);  break;
        case R_TANH:     RDL(R_TANH);     break;
        case R_BOTH:     RDL(R_BOTH);     break;
        case R_RS:       RDL(R_RS);       break;
    }
#undef RDL
}

static void tc(const float* in, __bf16* out, int R, int C, const int* flag, hipStream_t s)
{
    dim3 grid(C/32, R/32), block(256);
    tconv_ld_k<<<grid, block, 0, s>>>(in, out, R, C, R, 0, flag);
}

extern "C" void kernel_launch(void* const* d_in, const int* in_sizes, int n_in,
                              void* d_out, int out_size, void* d_ws, size_t ws_size,
                              hipStream_t stream)
{
    const float* raw   = (const float*)d_in[0];
    const float* spd   = (const float*)d_in[1];
    const float* dn_W1 = (const float*)d_in[2];
    const float* dn_b1 = (const float*)d_in[3];
    const float* dn_W2 = (const float*)d_in[4];
    const float* dn_b2 = (const float*)d_in[5];
    const float* q_W1  = (const float*)d_in[6];
    const float* q_b1  = (const float*)d_in[7];
    const float* q_W2  = (const float*)d_in[8];
    const float* q_b2  = (const float*)d_in[9];
    const float* e_Win = (const float*)d_in[10];
    const float* e_bin = (const float*)d_in[11];
    const float* Wq    = (const float*)d_in[12];
    const float* Wk    = (const float*)d_in[13];
    const float* Wv    = (const float*)d_in[14];
    const float* Wo    = (const float*)d_in[15];
    const float* bq    = (const float*)d_in[16];
    const float* bk    = (const float*)d_in[17];
    const float* bv    = (const float*)d_in[18];
    const float* bo    = (const float*)d_in[19];
    const float* ln1_g = (const float*)d_in[20];
    const float* ln1_b = (const float*)d_in[21];
    const float* ln2_g = (const float*)d_in[22];
    const float* ln2_b = (const float*)d_in[23];
    const float* f_W1  = (const float*)d_in[24];
    const float* f_b1  = (const float*)d_in[25];
    const float* f_W2  = (const float*)d_in[26];
    const float* f_b2  = (const float*)d_in[27];
    const float* ci_T  = (const float*)d_in[28];
    const float* ci_G  = (const float*)d_in[29];
    const int*   interact = (const int*)d_in[30];
    (void)in_sizes; (void)n_in; (void)ws_size; (void)out_size;

    float* out = (float*)d_out;
    float* ws = (float*)d_ws;
    size_t off = 0;
    auto af32 = [&](size_t n) { float* p = ws + off; off += n; return p; };
    auto ab16 = [&](size_t n) { __bf16* p = (__bf16*)(ws + off); off += (n + 1) / 2; return p; };

    float*  S        = af32((size_t)NC * NC);   // gram / split-K partials / flash partials
    float*  denoised = af32((size_t)NC * GG);
    __bf16* simB     = ab16((size_t)NC * NC);   // unnorm sim p; later reused as spatial bf16
    __bf16* ciS      = ab16((size_t)NC * NC);
    __bf16* T1b      = ab16((size_t)NC * FF);
    float*  Tq       = af32((size_t)NC * 128);
    float*  quality  = af32(NC);
    float*  rowinv   = af32(NC);
    float*  h        = af32((size_t)NC * DM);
    __bf16* hb       = ab16((size_t)NC * DM);
    __bf16* qkvB     = ab16((size_t)NC * 384);
    __bf16* vbT      = ab16((size_t)DM * NC);
    __bf16* obB      = ab16((size_t)NC * DM);
    float*  t2       = af32((size_t)NC * DM);
    __bf16* rawB     = ab16((size_t)NC * GG);
    __bf16* denT     = ab16((size_t)GG * NC);
    __bf16* smoT     = ab16((size_t)GG * NC);
    __bf16* Ubig     = ab16((size_t)NC * 2*GG);
    __bf16* TembB    = ab16((size_t)NC * DM);
    float*  sqbuf    = af32(NC);
    __bf16* dnW1T    = ab16((size_t)FF * GG);
    __bf16* dnW2T    = ab16((size_t)GG * FF);
    __bf16* eWinT    = ab16((size_t)DM * GG);
    __bf16* qW1pT    = ab16((size_t)128 * GG);
    float*  qb1p     = af32(128);
    __bf16* Wqkv     = ab16((size_t)LL * 384 * DM);
    float*  bqkv     = af32((size_t)LL * 384);
    __bf16* WoT      = ab16((size_t)LL * DM * DM);
    __bf16* fW1T     = ab16((size_t)LL * FF * DM);
    __bf16* fW2T     = ab16((size_t)LL * DM * FF);
    __bf16* ciTT     = ab16((size_t)NHCI * DM * DM);
    __bf16* ciGbigT  = ab16((size_t)GG * 2*GG);

    // flash partial buffers live inside S (dead during transformer phase)
    float* Opart = S;                                   // NS*NC*DM fp32
    float* lpart = S + (size_t)NS*NC*DM;                // NS*HH*NC
    // spatial bf16 aliases simB (simB is dead after the smoothed reduce)
    __bf16* spB = simB;

    // ---- packs / conversions ----
    tc(dn_W1, dnW1T, GG, FF, nullptr, stream);
    tc(dn_W2, dnW2T, FF, GG, nullptr, stream);
    tc(e_Win, eWinT, GG, DM, nullptr, stream);
    qw1pad_k<<<(128*GG)/256, 256, 0, stream>>>(q_W1, qW1pT);
    padb_k<<<1, 128, 0, stream>>>(q_b1, qb1p);
    qkvpack_k<<<dim3(192, LL), 256, 0, stream>>>(Wq, Wk, Wv, bq, bk, bv, Wqkv, bqkv);
    for (int l = 0; l < LL; ++l) {
        tc(Wo + (size_t)l*DM*DM, WoT + (size_t)l*DM*DM, DM, DM, nullptr, stream);
        tc(f_W1 + (size_t)l*DM*FF, fW1T + (size_t)l*FF*DM, DM, FF, nullptr, stream);
        tc(f_W2 + (size_t)l*FF*DM, fW2T + (size_t)l*DM*FF, FF, DM, nullptr, stream);
    }
    conv_k<<<(NC*GG/4 + 255)/256, 256, 0, stream>>>(raw, rawB, NC*GG/4);

    // ---- CellDenoise (split-K) ----
    sk(rawB, GG, dnW1T, GG, S, NC, FF, GG, 8, nullptr, stream);
    red(R_RELU_B16, S, NC, FF, 8, dn_b1, nullptr, 0, nullptr, T1b, FF, 0, nullptr, 1.f, stream);
    sk(T1b, FF, dnW2T, FF, S, NC, GG, FF, 4, nullptr, stream);
    red(R_BIASRES, S, NC, GG, 4, dn_b2, raw, GG, denoised, nullptr, GG, 0, nullptr, 1.f, stream);
    // ---- CellQualify (split-K, padded N=128) ----
    sk(rawB, GG, qW1pT, GG, S, NC, 128, GG, 8, nullptr, stream);
    red(R_TANH, S, NC, 128, 8, qb1p, nullptr, 0, Tq, nullptr, 128, 0, nullptr, 1.f, stream);
    qualify2_k<<<NC, 64, 0, stream>>>(Tq, q_W2, q_b2, quality);
    // ---- CellEmbed input proj (split-K) ----
    sk(rawB, GG, eWinT, GG, S, NC, 128, GG, 8, nullptr, stream);
    red(R_BOTH, S, NC, 128, 8, e_bin, nullptr, 0, h, hb, 128, 0, nullptr, 1.f, stream);
    // ---- Transformer layers ----
    for (int l = 0; l < LL; ++l) {
        mg(MM_BIAS_B16, hb, DM, Wqkv + (size_t)l*384*DM, DM, bqkv + l*384,
           nullptr, qkvB, 384, NC, 384, DM, 1.f, nullptr, nullptr, stream);
        tconv16_k<<<dim3(DM/32, NC/32), 256, 0, stream>>>(qkvB, 384, 256, vbT, NC);
        flashp_k<<<dim3(NC/64, HH, NS), 256, 0, stream>>>(qkvB, qkvB + 128, 384, vbT,
                                                          Opart, lpart);
        flashmerge_k<<<(NC*DM)/256, 256, 0, stream>>>(Opart, lpart, obB);
        mg(MM_BIAS, obB, DM, WoT + (size_t)l*DM*DM, DM, bo + l*DM,
           t2, nullptr, DM, NC, DM, DM, 1.f, nullptr, nullptr, stream);
        add_ln_k<<<NC, 64, 0, stream>>>(h, hb, t2, ln1_g + l*DM, ln1_b + l*DM);
        mg(MM_RELU_B16, hb, DM, fW1T + (size_t)l*FF*DM, DM, f_b1 + l*FF,
           nullptr, T1b, FF, NC, FF, DM, 1.f, nullptr, nullptr, stream);
        mg(MM_BIAS, T1b, FF, fW2T + (size_t)l*DM*FF, FF, f_b2 + l*DM,
           t2, nullptr, DM, NC, DM, FF, 1.f, nullptr, nullptr, stream);
        add_ln_k<<<NC, 64, 0, stream>>>(h, hb, t2, ln2_g + l*DM, ln2_b + l*DM);
    }
    // ---- CellSmooth ----
    rownorm_k<<<NC, 64, 0, stream>>>(h, sqbuf);
    mg(MM_NONE, hb, DM, hb, DM, nullptr, S, nullptr, NC, NC, NC, DM, 1.f, nullptr, nullptr, stream);
    dist_softmax_k<<<NC, 256, 0, stream>>>(S, sqbuf, quality, simB, rowinv, NC);
    tc(denoised, denT, NC, GG, nullptr, stream);
    sk(simB, NC, denT, NC, S, NC, GG, NC, 4, nullptr, stream);
    red(R_RS, S, NC, GG, 4, nullptr, rowinv, 0, out, nullptr, GG, 0, nullptr, 1.f, stream);
    // ---- CellInteract (gated on *interact) ----
    tc(out, smoT, NC, GG, interact, stream);
    spconv_k<<<(NC*NC/4)/256, 256, 0, stream>>>(spd, spB, interact);   // overwrites simB
    for (int hh = 0; hh < NHCI; ++hh) {
        tc(ci_T + (size_t)hh*DM*DM, ciTT + (size_t)hh*DM*DM, DM, DM, interact, stream);
        dim3 gg(GG/32, GG/32);
        tconv_ld_k<<<gg, 256, 0, stream>>>(ci_G + (size_t)hh*GG*GG, ciGbigT, GG, GG,
                                           2*GG, hh*GG, interact);
    }
    for (int hh = 0; hh < NHCI; ++hh) {
        mg(MM_B16, hb, DM, ciTT + (size_t)hh*DM*DM, DM, nullptr,
           nullptr, TembB, DM, NC, DM, DM, 1.f, nullptr, interact, stream);
        mg(MM_SIGSP_B16, TembB, DM, hb, DM, nullptr,
           nullptr, ciS, NC, NC, NC, DM, 1.f, spB, interact, stream);
        sk(ciS, NC, smoT, NC, S, NC, GG, NC, 4, interact, stream);
        red(R_B16LD, S, NC, GG, 4, nullptr, nullptr, 0, nullptr, Ubig, 2*GG, hh*GG,
            interact, 1.f, stream);
    }
    sk(Ubig, 2*GG, ciGbigT, 2*GG, S, NC, GG, 2*GG, 4, interact, stream);
    red(R_ACCG, S, NC, GG, 4, nullptr, nullptr, 0, out, nullptr, GG, 0,
        interact, 1.0f/1024.f, stream);
}

// Round 7
// 726.828 us; speedup vs baseline: 1.4193x; 1.0584x over previous
//
#include <hip/hip_runtime.h>
#include <hip/hip_bf16.h>

#define NC 4096
#define GG 1024
#define DM 128
#define HH 4
#define HDIM 32
#define FF 512
#define LL 2
#define NHCI 2
#define NS 8
#define LS2 (100.0f*100.0f)

typedef __bf16 bf16x8 __attribute__((ext_vector_type(8)));
typedef __bf16 bf16x4 __attribute__((ext_vector_type(4)));
typedef float  f32x4  __attribute__((ext_vector_type(4)));

// bijective XCD-chunk swizzle (m204)
__device__ __forceinline__ int xcd_swz(int orig, int nwg)
{
    int q = nwg >> 3, r = nwg & 7;
    int xcd = orig & 7, idx = orig >> 3;
    return (xcd < r ? xcd*(q+1) : r*(q+1) + (xcd-r)*q) + idx;
}

// ================= bf16 MFMA GEMM (m97 structure, fused epilogues) ==========
// aux1: bias (per-col) or quality (per-col). aux2: spd (row-major fp32) or sq (per-row).
enum { MM_NONE=0, MM_BIAS, MM_BIAS_B16, MM_RELU_B16, MM_B16, MM_SIGSP_B16, MM_DIST };

template<int EM>
__launch_bounds__(256)
__global__ void mgemm_k(const __bf16* __restrict__ A, int lda,
                        const __bf16* __restrict__ BT, int ldb,
                        const float* __restrict__ aux1,
                        float* __restrict__ C, __bf16* __restrict__ Cb, int ldc,
                        int M, int N, int K, float alpha,
                        const float* __restrict__ aux2,
                        const int* __restrict__ flag)
{
    if (flag && *flag == 0) return;
    __shared__ __align__(16) __bf16 As[128][32];
    __shared__ __align__(16) __bf16 Bs[128][32];
    const int tid  = threadIdx.x;
    const int lane = tid & 63;
    const int wid  = tid >> 6;
    const int wm = wid >> 1, wn = wid & 1;
    const int nwg  = gridDim.x * gridDim.y;
    const int wg   = xcd_swz(blockIdx.y * gridDim.x + blockIdx.x, nwg);
    const int bm = (wg / gridDim.x) * 128, bn = (wg % gridDim.x) * 128;

    f32x4 acc[4][4];
    #pragma unroll
    for (int m=0;m<4;m++)
        #pragma unroll
        for (int n=0;n<4;n++) acc[m][n] = (f32x4){0.f,0.f,0.f,0.f};

    const int c0 = wid*64 + lane, c1 = c0 + 256;
    const __bf16* ga0 = A  + (size_t)(bm + (c0>>2))*lda + ((c0&3)<<3);
    const __bf16* ga1 = A  + (size_t)(bm + (c1>>2))*lda + ((c1&3)<<3);
    const __bf16* gb0 = BT + (size_t)(bn + (c0>>2))*ldb + ((c0&3)<<3);
    const __bf16* gb1 = BT + (size_t)(bn + (c1>>2))*ldb + ((c1&3)<<3);
    auto* lA = (__attribute__((address_space(3))) __bf16*)&As[0][0];
    auto* lB = (__attribute__((address_space(3))) __bf16*)&Bs[0][0];
    auto* lA0 = (__attribute__((address_space(3))) void*)(lA + (size_t)(wid*64)*8);
    auto* lA1 = (__attribute__((address_space(3))) void*)(lA + (size_t)(256 + wid*64)*8);
    auto* lB0 = (__attribute__((address_space(3))) void*)(lB + (size_t)(wid*64)*8);
    auto* lB1 = (__attribute__((address_space(3))) void*)(lB + (size_t)(256 + wid*64)*8);

    const int r  = lane & 15;
    const int kb = lane >> 4;
    const int arow = wm*64, brow = wn*64;

    for (int k0 = 0; k0 < K; k0 += 32) {
        __builtin_amdgcn_global_load_lds((const __attribute__((address_space(1))) void*)ga0, lA0, 16, 0, 0);
        __builtin_amdgcn_global_load_lds((const __attribute__((address_space(1))) void*)ga1, lA1, 16, 0, 0);
        __builtin_amdgcn_global_load_lds((const __attribute__((address_space(1))) void*)gb0, lB0, 16, 0, 0);
        __builtin_amdgcn_global_load_lds((const __attribute__((address_space(1))) void*)gb1, lB1, 16, 0, 0);
        ga0 += 32; ga1 += 32; gb0 += 32; gb1 += 32;
        __syncthreads();
        bf16x8 af[4], bfr[4];
        #pragma unroll
        for (int m=0;m<4;m++) af[m]  = *(const bf16x8*)&As[arow + m*16 + r][kb*8];
        #pragma unroll
        for (int n=0;n<4;n++) bfr[n] = *(const bf16x8*)&Bs[brow + n*16 + r][kb*8];
        #pragma unroll
        for (int m=0;m<4;m++)
            #pragma unroll
            for (int n=0;n<4;n++)
                acc[m][n] = __builtin_amdgcn_mfma_f32_16x16x32_bf16(af[m], bfr[n], acc[m][n], 0, 0, 0);
        __syncthreads();
    }

    const int crow = (lane >> 4) * 4;
    const int ccol = lane & 15;
    #pragma unroll
    for (int m=0;m<4;m++) {
        #pragma unroll
        for (int n=0;n<4;n++) {
            const int gn = bn + wn*64 + n*16 + ccol;
            #pragma unroll
            for (int q=0;q<4;q++) {
                const int gm = bm + wm*64 + m*16 + crow + q;
                float v = acc[m][n][q] * alpha;
                if (EM==MM_BIAS || EM==MM_BIAS_B16 || EM==MM_RELU_B16) v += aux1[gn];
                if (EM==MM_RELU_B16) v = fmaxf(v, 0.f);
                if (EM==MM_SIGSP_B16) {
                    v = 1.f/(1.f + __expf(-v));
                    v *= __expf(aux2[(size_t)gm*(size_t)N + gn] * (-1.f/LS2));
                }
                if (EM==MM_DIST) {
                    float d2 = fmaxf(aux2[gm] + aux2[gn] - 2.f*v, 0.f);
                    v = __expf(aux1[gn] - sqrtf(d2));
                }
                const size_t ci = (size_t)gm*ldc + gn;
                if (EM==MM_NONE || EM==MM_BIAS) C[ci] = v;
                else Cb[ci] = (__bf16)v;
            }
        }
    }
}

// ========== split-K MFMA GEMM: bf16 partials to P[ks][M][N] ================
__launch_bounds__(256)
__global__ void mgemm_sk(const __bf16* __restrict__ A, int lda,
                         const __bf16* __restrict__ BT, int ldb,
                         __bf16* __restrict__ P, int M, int N, int KC,
                         const int* __restrict__ flag)
{
    if (flag && *flag == 0) return;
    __shared__ __align__(16) __bf16 As[128][32];
    __shared__ __align__(16) __bf16 Bs[128][32];
    const int tid  = threadIdx.x;
    const int lane = tid & 63;
    const int wid  = tid >> 6;
    const int wm = wid >> 1, wn = wid & 1;
    const int nwg  = gridDim.x * gridDim.y;
    const int wg   = xcd_swz(blockIdx.y * gridDim.x + blockIdx.x, nwg);
    const int bm = (wg / gridDim.x) * 128, bn = (wg % gridDim.x) * 128;
    const size_t koff = (size_t)blockIdx.z * KC;

    f32x4 acc[4][4];
    #pragma unroll
    for (int m=0;m<4;m++)
        #pragma unroll
        for (int n=0;n<4;n++) acc[m][n] = (f32x4){0.f,0.f,0.f,0.f};

    const int c0 = wid*64 + lane, c1 = c0 + 256;
    const __bf16* ga0 = A  + (size_t)(bm + (c0>>2))*lda + koff + ((c0&3)<<3);
    const __bf16* ga1 = A  + (size_t)(bm + (c1>>2))*lda + koff + ((c1&3)<<3);
    const __bf16* gb0 = BT + (size_t)(bn + (c0>>2))*ldb + koff + ((c0&3)<<3);
    const __bf16* gb1 = BT + (size_t)(bn + (c1>>2))*ldb + koff + ((c1&3)<<3);
    auto* lA = (__attribute__((address_space(3))) __bf16*)&As[0][0];
    auto* lB = (__attribute__((address_space(3))) __bf16*)&Bs[0][0];
    auto* lA0 = (__attribute__((address_space(3))) void*)(lA + (size_t)(wid*64)*8);
    auto* lA1 = (__attribute__((address_space(3))) void*)(lA + (size_t)(256 + wid*64)*8);
    auto* lB0 = (__attribute__((address_space(3))) void*)(lB + (size_t)(wid*64)*8);
    auto* lB1 = (__attribute__((address_space(3))) void*)(lB + (size_t)(256 + wid*64)*8);

    const int r  = lane & 15;
    const int kb = lane >> 4;
    const int arow = wm*64, brow = wn*64;

    for (int k0 = 0; k0 < KC; k0 += 32) {
        __builtin_amdgcn_global_load_lds((const __attribute__((address_space(1))) void*)ga0, lA0, 16, 0, 0);
        __builtin_amdgcn_global_load_lds((const __attribute__((address_space(1))) void*)ga1, lA1, 16, 0, 0);
        __builtin_amdgcn_global_load_lds((const __attribute__((address_space(1))) void*)gb0, lB0, 16, 0, 0);
        __builtin_amdgcn_global_load_lds((const __attribute__((address_space(1))) void*)gb1, lB1, 16, 0, 0);
        ga0 += 32; ga1 += 32; gb0 += 32; gb1 += 32;
        __syncthreads();
        bf16x8 af[4], bfr[4];
        #pragma unroll
        for (int m=0;m<4;m++) af[m]  = *(const bf16x8*)&As[arow + m*16 + r][kb*8];
        #pragma unroll
        for (int n=0;n<4;n++) bfr[n] = *(const bf16x8*)&Bs[brow + n*16 + r][kb*8];
        #pragma unroll
        for (int m=0;m<4;m++)
            #pragma unroll
            for (int n=0;n<4;n++)
                acc[m][n] = __builtin_amdgcn_mfma_f32_16x16x32_bf16(af[m], bfr[n], acc[m][n], 0, 0, 0);
        __syncthreads();
    }

    __bf16* Pz = P + (size_t)blockIdx.z * M * N;
    const int crow = (lane >> 4) * 4;
    const int ccol = lane & 15;
    #pragma unroll
    for (int m=0;m<4;m++)
        #pragma unroll
        for (int n=0;n<4;n++) {
            const int gn = bn + wn*64 + n*16 + ccol;
            #pragma unroll
            for (int q=0;q<4;q++) {
                const int gm = bm + wm*64 + m*16 + crow + q;
                Pz[(size_t)gm*N + gn] = (__bf16)acc[m][n][q];
            }
        }
}

// ========== split-K reduce (bf16 partials) with fused epilogues ============
enum { R_F32=0, R_B16LD, R_ACCG, R_RELU_B16, R_BIASRES, R_TANH, R_BOTH, R_RS,
       R_BIAS16, R_BIASF };

template<int RE>
__launch_bounds__(256)
__global__ void redk_k(const __bf16* __restrict__ P, int M, int N, int KS,
                       const float* __restrict__ bias,
                       const float* __restrict__ res, int ldres,
                       float* __restrict__ C, __bf16* __restrict__ Cb,
                       int ldout, int coff,
                       const int* __restrict__ flag, float alpha)
{
    if (flag && *flag == 0) return;
    int i = blockIdx.x*256 + threadIdx.x;
    int total = (M*N) >> 2;
    if (i >= total) return;
    int row = i / (N >> 2);
    int c4  = (i - row*(N >> 2)) << 2;
    f32x4 s = {0.f,0.f,0.f,0.f};
    for (int ks = 0; ks < KS; ++ks) {
        bf16x4 t = *(const bf16x4*)(P + ((size_t)ks*M + row)*N + c4);
        s[0] += (float)t[0]; s[1] += (float)t[1];
        s[2] += (float)t[2]; s[3] += (float)t[3];
    }
    #pragma unroll
    for (int j=0;j<4;j++) {
        int col = c4 + j;
        float v = s[j];
        if (RE==R_RELU_B16) v = fmaxf(v + bias[col], 0.f);
        if (RE==R_BIASRES)  v = v + bias[col] + res[(size_t)row*ldres + col];
        if (RE==R_TANH)     v = tanhf(v + bias[col]);
        if (RE==R_BOTH || RE==R_BIAS16 || RE==R_BIASF) v = v + bias[col];
        if (RE==R_RS)       v = v * res[row];      // res = per-row scale
        size_t o = (size_t)row*ldout + coff + col;
        if (RE==R_F32 || RE==R_BIASRES || RE==R_TANH || RE==R_RS || RE==R_BIASF) C[o] = v;
        if (RE==R_BOTH) { C[o] = v; Cb[o] = (__bf16)v; }
        if (RE==R_B16LD || RE==R_RELU_B16 || RE==R_BIAS16) Cb[o] = (__bf16)v;
        if (RE==R_ACCG) C[o] += v * alpha;
    }
}

// ================= flash attention, KV-split partials, no-max softmax =======
__launch_bounds__(256)
__global__ void flashp_k(const __bf16* __restrict__ Q, const __bf16* __restrict__ Kb,
                         int ldqk, const __bf16* __restrict__ VT,
                         float* __restrict__ Op, float* __restrict__ lp)
{
    __shared__ __align__(16) __bf16 Plds[4][16][72];
    const int lane = threadIdx.x & 63, w = threadIdx.x >> 6;
    const int hd = blockIdx.y, sp = blockIdx.z;
    const int q0 = blockIdx.x * 64 + w * 16;
    const int c  = lane & 15, kb = lane >> 4;
    const float scale = 0.17677669529663687f;

    const bf16x8 aq = *(const bf16x8*)&Q[(size_t)(q0 + c)*ldqk + hd*HDIM + kb*8];
    bf16x8 ones;
    #pragma unroll
    for (int j=0;j<8;j++) ones[j] = (__bf16)1.0f;

    f32x4 oacc[2] = {(f32x4){0,0,0,0}, (f32x4){0,0,0,0}};
    f32x4 lacc = (f32x4){0,0,0,0};

    const int kv0 = sp * (NC/NS), kv1 = kv0 + NC/NS;
    for (int kv = kv0; kv < kv1; kv += 64) {
        f32x4 s[4];
        #pragma unroll
        for (int n=0;n<4;n++) {
            bf16x8 bk = *(const bf16x8*)&Kb[(size_t)(kv + n*16 + c)*ldqk + hd*HDIM + kb*8];
            s[n] = __builtin_amdgcn_mfma_f32_16x16x32_bf16(aq, bk, (f32x4){0,0,0,0}, 0, 0, 0);
        }
        #pragma unroll
        for (int n=0;n<4;n++)
            #pragma unroll
            for (int q=0;q<4;q++)
                Plds[w][kb*4+q][n*16+c] = (__bf16)__expf(s[n][q]*scale);
        #pragma unroll
        for (int ks=0;ks<2;ks++) {
            bf16x8 ap = *(const bf16x8*)&Plds[w][c][ks*32 + kb*8];
            #pragma unroll
            for (int n2=0;n2<2;n2++) {
                bf16x8 bv = *(const bf16x8*)&VT[(size_t)(hd*HDIM + n2*16 + c)*NC + kv + ks*32 + kb*8];
                oacc[n2] = __builtin_amdgcn_mfma_f32_16x16x32_bf16(ap, bv, oacc[n2], 0, 0, 0);
            }
            lacc = __builtin_amdgcn_mfma_f32_16x16x32_bf16(ap, ones, lacc, 0, 0, 0);
        }
    }
    float* Oz = Op + (size_t)sp * NC * DM;
    #pragma unroll
    for (int n2=0;n2<2;n2++)
        #pragma unroll
        for (int q=0;q<4;q++)
            Oz[(size_t)(q0 + kb*4 + q)*DM + hd*HDIM + n2*16 + c] = oacc[n2][q];
    if (c == 0) {
        #pragma unroll
        for (int q=0;q<4;q++)
            lp[((size_t)sp*HH + hd)*NC + q0 + kb*4 + q] = lacc[q];
    }
}

// merge NS partials -> O bf16 [NC][DM]
__launch_bounds__(256)
__global__ void flashmerge_k(const float* __restrict__ Op, const float* __restrict__ lp,
                             __bf16* __restrict__ O)
{
    int idx = blockIdx.x*256 + threadIdx.x;
    int row = idx >> 7, col = idx & 127, hd = col >> 5;
    float L = 0.f, acc = 0.f;
    #pragma unroll
    for (int s=0;s<NS;s++) {
        L   += lp[((size_t)s*HH + hd)*NC + row];
        acc += Op[(size_t)s*NC*DM + idx];
    }
    O[idx] = (__bf16)(acc / L);
}

// ================= small kernels =================
__global__ void qualify2_k(const float* __restrict__ Tq, const float* __restrict__ w,
                           const float* __restrict__ b2, float* __restrict__ quality)
{
    int row = blockIdx.x, lane = threadIdx.x;
    float v = Tq[row*128 + lane] * w[lane];
    #pragma unroll
    for (int o=32;o>0;o>>=1) v += __shfl_down(v, o);
    if (lane == 0) quality[row] = v + b2[0];
}

__global__ void qw1pad_k(const float* __restrict__ W, __bf16* __restrict__ out)
{
    int idx = blockIdx.x*256 + threadIdx.x;
    int k = idx & 1023, j = idx >> 10;
    out[(size_t)j*GG + k] = (j < 64) ? (__bf16)W[(size_t)k*64 + j] : (__bf16)0.f;
}

__global__ void padb_k(const float* __restrict__ b, float* __restrict__ out)
{
    int i = threadIdx.x;
    out[i] = (i < 64) ? b[i] : 0.f;
}

__global__ void qkvpack_k(const float* __restrict__ Wq, const float* __restrict__ Wk,
                          const float* __restrict__ Wv,
                          const float* __restrict__ bq, const float* __restrict__ bk,
                          const float* __restrict__ bv,
                          __bf16* __restrict__ WT, float* __restrict__ bb)
{
    int l = blockIdx.y;
    int i = blockIdx.x*256 + threadIdx.x;
    int n = i >> 7, k = i & 127;
    const float* W = (n < 128) ? Wq : (n < 256 ? Wk : Wv);
    int nn = n & 127;
    WT[(size_t)l*384*128 + i] = (__bf16)W[(size_t)l*DM*DM + (size_t)k*DM + nn];
    if (i < 384) {
        const float* b = (i < 128) ? bq : (i < 256 ? bk : bv);
        bb[l*384 + i] = b[l*DM + (i & 127)];
    }
}

__global__ void rownorm_k(const float* __restrict__ h, float* __restrict__ sq)
{
    int row = blockIdx.x, lane = threadIdx.x;
    float x0 = h[row*DM + lane], x1 = h[row*DM + lane + 64];
    float v = x0*x0 + x1*x1;
    #pragma unroll
    for (int o=32;o>0;o>>=1) v += __shfl_down(v, o);
    if (lane == 0) sq[row] = v;
}

__global__ void add_ln_k(float* __restrict__ h, __bf16* __restrict__ hb,
                         const float* __restrict__ t,
                         const float* __restrict__ g, const float* __restrict__ b)
{
    int row = blockIdx.x, lane = threadIdx.x;
    float x0 = h[row*DM + lane]      + t[row*DM + lane];
    float x1 = h[row*DM + lane + 64] + t[row*DM + lane + 64];
    float s = x0 + x1, ss = x0*x0 + x1*x1;
    #pragma unroll
    for (int o=32;o>0;o>>=1) { s += __shfl_down(s, o); ss += __shfl_down(ss, o); }
    s = __shfl(s, 0); ss = __shfl(ss, 0);
    float mean = s * (1.f/128.f);
    float var  = ss * (1.f/128.f) - mean*mean;
    float inv  = rsqrtf(var + 1e-5f);
    float y0 = g[lane]      * (x0 - mean) * inv + b[lane];
    float y1 = g[lane + 64] * (x1 - mean) * inv + b[lane + 64];
    h[row*DM + lane]       = y0;  h[row*DM + lane + 64]  = y1;
    hb[row*DM + lane]      = (__bf16)y0;
    hb[row*DM + lane + 64] = (__bf16)y1;
}

// rowinv[row] = 1 / sum_j simB[row][j]
__launch_bounds__(256)
__global__ void rowsum16_k(const __bf16* __restrict__ P, float* __restrict__ rinv)
{
    __shared__ float sl[4];
    size_t row = blockIdx.x;
    const __bf16* p = P + row * (size_t)NC;
    int tid = threadIdx.x;
    float sum = 0.f;
    for (int j = tid*8; j < NC; j += 256*8) {
        bf16x8 v = *(const bf16x8*)&p[j];
        #pragma unroll
        for (int k=0;k<8;k++) sum += (float)v[k];
    }
    #pragma unroll
    for (int o=32;o>0;o>>=1) sum += __shfl_down(sum, o);
    if ((tid & 63) == 0) sl[tid >> 6] = sum;
    __syncthreads();
    if (tid == 0) rinv[row] = 1.f / (sl[0] + sl[1] + sl[2] + sl[3]);
}

__global__ void tconv_ld_k(const float* __restrict__ in, __bf16* __restrict__ out,
                           int R, int C, int ldout, int coff,
                           const int* __restrict__ flag)
{
    if (flag && *flag == 0) return;
    __shared__ float tile[32][33];
    int bc = blockIdx.x * 32, br = blockIdx.y * 32;
    int tx = threadIdx.x & 31, ty = threadIdx.x >> 5;
    #pragma unroll
    for (int i=0;i<4;i++)
        tile[ty + 8*i][tx] = in[(size_t)(br + ty + 8*i)*C + bc + tx];
    __syncthreads();
    #pragma unroll
    for (int i=0;i<4;i++)
        out[(size_t)(bc + ty + 8*i)*ldout + coff + br + tx] = (__bf16)tile[tx][ty + 8*i];
}

__global__ void tconv16_k(const __bf16* __restrict__ in, int ldin, int coff,
                          __bf16* __restrict__ out, int R)
{
    __shared__ __bf16 tile[32][33];
    int bc = blockIdx.x * 32, br = blockIdx.y * 32;
    int tx = threadIdx.x & 31, ty = threadIdx.x >> 5;
    #pragma unroll
    for (int i=0;i<4;i++)
        tile[ty + 8*i][tx] = in[(size_t)(br + ty + 8*i)*ldin + coff + bc + tx];
    __syncthreads();
    #pragma unroll
    for (int i=0;i<4;i++)
        out[(size_t)(bc + ty + 8*i)*R + br + tx] = tile[tx][ty + 8*i];
}

__global__ void conv_k(const float* __restrict__ in, __bf16* __restrict__ out, int n4)
{
    int i = blockIdx.x * 256 + threadIdx.x;
    if (i < n4) {
        float4 v = ((const float4*)in)[i];
        bf16x4 o = {(__bf16)v.x, (__bf16)v.y, (__bf16)v.z, (__bf16)v.w};
        ((bf16x4*)out)[i] = o;
    }
}

// ================= launchers =================
static void mg(int em, const __bf16* A, int lda, const __bf16* BT, int ldb,
               const float* aux1, float* C, __bf16* Cb, int ldc,
               int M, int N, int K, float alpha,
               const float* aux2, const int* flag, hipStream_t s)
{
    dim3 grid(N/128, M/128), block(256);
#define MGL(E) mgemm_k<E><<<grid,block,0,s>>>(A,lda,BT,ldb,aux1,C,Cb,ldc,M,N,K,alpha,aux2,flag)
    switch (em) {
        case MM_NONE:      MGL(MM_NONE);      break;
        case MM_BIAS:      MGL(MM_BIAS);      break;
        case MM_BIAS_B16:  MGL(MM_BIAS_B16);  break;
        case MM_RELU_B16:  MGL(MM_RELU_B16);  break;
        case MM_B16:       MGL(MM_B16);       break;
        case MM_SIGSP_B16: MGL(MM_SIGSP_B16); break;
        case MM_DIST:      MGL(MM_DIST);      break;
    }
#undef MGL
}

static void sk(const __bf16* A, int lda, const __bf16* BT, int ldb,
               __bf16* P, int M, int N, int K, int KS, const int* flag, hipStream_t s)
{
    dim3 grid(N/128, M/128, KS), block(256);
    mgemm_sk<<<grid, block, 0, s>>>(A, lda, BT, ldb, P, M, N, K/KS, flag);
}

static void red(int re, const __bf16* P, int M, int N, int KS,
                const float* bias, const float* res, int ldres,
                float* C, __bf16* Cb, int ldout, int coff,
                const int* flag, float alpha, hipStream_t s)
{
    int blocks = (M*N/4 + 255) / 256;
#define RDL(E) redk_k<E><<<blocks,256,0,s>>>(P,M,N,KS,bias,res,ldres,C,Cb,ldout,coff,flag,alpha)
    switch (re) {
        case R_F32:      RDL(R_F32);      break;
        case R_B16LD:    RDL(R_B16LD);    break;
        case R_ACCG:     RDL(R_ACCG);     break;
        case R_RELU_B16: RDL(R_RELU_B16); break;
        case R_BIASRES:  RDL(R_BIASRES);  break;
        case R_TANH:     RDL(R_TANH);     break;
        case R_BOTH:     RDL(R_BOTH);     break;
        case R_RS:       RDL(R_RS);       break;
        case R_BIAS16:   RDL(R_BIAS16);   break;
        case R_BIASF:    RDL(R_BIASF);    break;
    }
#undef RDL
}

static void tc(const float* in, __bf16* out, int R, int C, const int* flag, hipStream_t s)
{
    dim3 grid(C/32, R/32), block(256);
    tconv_ld_k<<<grid, block, 0, s>>>(in, out, R, C, R, 0, flag);
}

extern "C" void kernel_launch(void* const* d_in, const int* in_sizes, int n_in,
                              void* d_out, int out_size, void* d_ws, size_t ws_size,
                              hipStream_t stream)
{
    const float* raw   = (const float*)d_in[0];
    const float* spd   = (const float*)d_in[1];
    const float* dn_W1 = (const float*)d_in[2];
    const float* dn_b1 = (const float*)d_in[3];
    const float* dn_W2 = (const float*)d_in[4];
    const float* dn_b2 = (const float*)d_in[5];
    const float* q_W1  = (const float*)d_in[6];
    const float* q_b1  = (const float*)d_in[7];
    const float* q_W2  = (const float*)d_in[8];
    const float* q_b2  = (const float*)d_in[9];
    const float* e_Win = (const float*)d_in[10];
    const float* e_bin = (const float*)d_in[11];
    const float* Wq    = (const float*)d_in[12];
    const float* Wk    = (const float*)d_in[13];
    const float* Wv    = (const float*)d_in[14];
    const float* Wo    = (const float*)d_in[15];
    const float* bq    = (const float*)d_in[16];
    const float* bk    = (const float*)d_in[17];
    const float* bv    = (const float*)d_in[18];
    const float* bo    = (const float*)d_in[19];
    const float* ln1_g = (const float*)d_in[20];
    const float* ln1_b = (const float*)d_in[21];
    const float* ln2_g = (const float*)d_in[22];
    const float* ln2_b = (const float*)d_in[23];
    const float* f_W1  = (const float*)d_in[24];
    const float* f_b1  = (const float*)d_in[25];
    const float* f_W2  = (const float*)d_in[26];
    const float* f_b2  = (const float*)d_in[27];
    const float* ci_T  = (const float*)d_in[28];
    const float* ci_G  = (const float*)d_in[29];
    const int*   interact = (const int*)d_in[30];
    (void)in_sizes; (void)n_in; (void)ws_size; (void)out_size;

    float* out = (float*)d_out;
    float* ws = (float*)d_ws;
    size_t off = 0;
    auto af32 = [&](size_t n) { float* p = ws + off; off += n; return p; };
    auto ab16 = [&](size_t n) { __bf16* p = (__bf16*)(ws + off); off += (n + 1) / 2; return p; };

    float*  S        = af32((size_t)NC * NC);   // split-K/flash partial arena
    float*  denoised = af32((size_t)NC * GG);
    __bf16* simB     = ab16((size_t)NC * NC);
    __bf16* ciS      = ab16((size_t)NC * NC);
    __bf16* T1b      = ab16((size_t)NC * FF);
    float*  Tq       = af32((size_t)NC * 128);
    float*  quality  = af32(NC);
    float*  rowinv   = af32(NC);
    float*  h        = af32((size_t)NC * DM);
    __bf16* hb       = ab16((size_t)NC * DM);
    __bf16* qkvB     = ab16((size_t)NC * 384);
    __bf16* vbT      = ab16((size_t)DM * NC);
    __bf16* obB      = ab16((size_t)NC * DM);
    float*  t2       = af32((size_t)NC * DM);
    __bf16* rawB     = ab16((size_t)NC * GG);
    __bf16* denT     = ab16((size_t)GG * NC);
    __bf16* smoT     = ab16((size_t)GG * NC);
    __bf16* Ubig     = ab16((size_t)NC * 2*GG);
    __bf16* TembB    = ab16((size_t)NC * DM);
    float*  sqbuf    = af32(NC);
    __bf16* dnW1T    = ab16((size_t)FF * GG);
    __bf16* dnW2T    = ab16((size_t)GG * FF);
    __bf16* eWinT    = ab16((size_t)DM * GG);
    __bf16* qW1pT    = ab16((size_t)128 * GG);
    float*  qb1p     = af32(128);
    __bf16* Wqkv     = ab16((size_t)LL * 384 * DM);
    float*  bqkv     = af32((size_t)LL * 384);
    __bf16* WoT      = ab16((size_t)LL * DM * DM);
    __bf16* fW1T     = ab16((size_t)LL * FF * DM);
    __bf16* fW2T     = ab16((size_t)LL * DM * FF);
    __bf16* ciTT     = ab16((size_t)NHCI * DM * DM);
    __bf16* ciGbigT  = ab16((size_t)GG * 2*GG);

    // partial arenas alias S
    __bf16* Pb    = (__bf16*)S;                     // bf16 split-K partials
    float*  Opart = S;                              // NS*NC*DM fp32 (flash)
    float*  lpart = S + (size_t)NS*NC*DM;           // NS*HH*NC

    // ---- packs / conversions ----
    tc(dn_W1, dnW1T, GG, FF, nullptr, stream);
    tc(dn_W2, dnW2T, FF, GG, nullptr, stream);
    tc(e_Win, eWinT, GG, DM, nullptr, stream);
    qw1pad_k<<<(128*GG)/256, 256, 0, stream>>>(q_W1, qW1pT);
    padb_k<<<1, 128, 0, stream>>>(q_b1, qb1p);
    qkvpack_k<<<dim3(192, LL), 256, 0, stream>>>(Wq, Wk, Wv, bq, bk, bv, Wqkv, bqkv);
    for (int l = 0; l < LL; ++l) {
        tc(Wo + (size_t)l*DM*DM, WoT + (size_t)l*DM*DM, DM, DM, nullptr, stream);
        tc(f_W1 + (size_t)l*DM*FF, fW1T + (size_t)l*FF*DM, DM, FF, nullptr, stream);
        tc(f_W2 + (size_t)l*FF*DM, fW2T + (size_t)l*DM*FF, FF, DM, nullptr, stream);
    }
    conv_k<<<(NC*GG/4 + 255)/256, 256, 0, stream>>>(raw, rawB, NC*GG/4);

    // ---- CellDenoise (split-K, bf16 partials) ----
    sk(rawB, GG, dnW1T, GG, Pb, NC, FF, GG, 8, nullptr, stream);
    red(R_RELU_B16, Pb, NC, FF, 8, dn_b1, nullptr, 0, nullptr, T1b, FF, 0, nullptr, 1.f, stream);
    sk(T1b, FF, dnW2T, FF, Pb, NC, GG, FF, 4, nullptr, stream);
    red(R_BIASRES, Pb, NC, GG, 4, dn_b2, raw, GG, denoised, nullptr, GG, 0, nullptr, 1.f, stream);
    // ---- CellQualify ----
    sk(rawB, GG, qW1pT, GG, Pb, NC, 128, GG, 8, nullptr, stream);
    red(R_TANH, Pb, NC, 128, 8, qb1p, nullptr, 0, Tq, nullptr, 128, 0, nullptr, 1.f, stream);
    qualify2_k<<<NC, 64, 0, stream>>>(Tq, q_W2, q_b2, quality);
    // ---- CellEmbed input proj ----
    sk(rawB, GG, eWinT, GG, Pb, NC, 128, GG, 8, nullptr, stream);
    red(R_BOTH, Pb, NC, 128, 8, e_bin, nullptr, 0, h, hb, 128, 0, nullptr, 1.f, stream);
    // ---- Transformer layers ----
    for (int l = 0; l < LL; ++l) {
        sk(hb, DM, Wqkv + (size_t)l*384*DM, DM, Pb, NC, 384, DM, 2, nullptr, stream);
        red(R_BIAS16, Pb, NC, 384, 2, bqkv + l*384, nullptr, 0, nullptr, qkvB, 384, 0,
            nullptr, 1.f, stream);
        tconv16_k<<<dim3(DM/32, NC/32), 256, 0, stream>>>(qkvB, 384, 256, vbT, NC);
        flashp_k<<<dim3(NC/64, HH, NS), 256, 0, stream>>>(qkvB, qkvB + 128, 384, vbT,
                                                          Opart, lpart);
        flashmerge_k<<<(NC*DM)/256, 256, 0, stream>>>(Opart, lpart, obB);
        sk(obB, DM, WoT + (size_t)l*DM*DM, DM, Pb, NC, DM, DM, 4, nullptr, stream);
        red(R_BIASF, Pb, NC, DM, 4, bo + l*DM, nullptr, 0, t2, nullptr, DM, 0,
            nullptr, 1.f, stream);
        add_ln_k<<<NC, 64, 0, stream>>>(h, hb, t2, ln1_g + l*DM, ln1_b + l*DM);
        mg(MM_RELU_B16, hb, DM, fW1T + (size_t)l*FF*DM, DM, f_b1 + l*FF,
           nullptr, T1b, FF, NC, FF, DM, 1.f, nullptr, nullptr, stream);
        sk(T1b, FF, fW2T + (size_t)l*DM*FF, FF, Pb, NC, DM, FF, 4, nullptr, stream);
        red(R_BIASF, Pb, NC, DM, 4, f_b2 + l*DM, nullptr, 0, t2, nullptr, DM, 0,
            nullptr, 1.f, stream);
        add_ln_k<<<NC, 64, 0, stream>>>(h, hb, t2, ln2_g + l*DM, ln2_b + l*DM);
    }
    // ---- CellSmooth (dist-softmax fused into gram epilogue) ----
    rownorm_k<<<NC, 64, 0, stream>>>(h, sqbuf);
    mg(MM_DIST, hb, DM, hb, DM, quality, nullptr, simB, NC, NC, NC, DM, 1.f,
       sqbuf, nullptr, stream);
    rowsum16_k<<<NC, 256, 0, stream>>>(simB, rowinv);
    tc(denoised, denT, NC, GG, nullptr, stream);
    sk(simB, NC, denT, NC, Pb, NC, GG, NC, 4, nullptr, stream);
    red(R_RS, Pb, NC, GG, 4, nullptr, rowinv, 0, out, nullptr, GG, 0, nullptr, 1.f, stream);
    // ---- CellInteract (gated on *interact) ----
    tc(out, smoT, NC, GG, interact, stream);
    for (int hh = 0; hh < NHCI; ++hh) {
        tc(ci_T + (size_t)hh*DM*DM, ciTT + (size_t)hh*DM*DM, DM, DM, interact, stream);
        dim3 gg(GG/32, GG/32);
        tconv_ld_k<<<gg, 256, 0, stream>>>(ci_G + (size_t)hh*GG*GG, ciGbigT, GG, GG,
                                           2*GG, hh*GG, interact);
    }
    for (int hh = 0; hh < NHCI; ++hh) {
        sk(hb, DM, ciTT + (size_t)hh*DM*DM, DM, Pb, NC, DM, DM, 4, interact, stream);
        red(R_B16LD, Pb, NC, DM, 4, nullptr, nullptr, 0, nullptr, TembB, DM, 0,
            interact, 1.f, stream);
        mg(MM_SIGSP_B16, TembB, DM, hb, DM, nullptr,
           nullptr, ciS, NC, NC, NC, DM, 1.f, spd, interact, stream);
        sk(ciS, NC, smoT, NC, Pb, NC, GG, NC, 4, interact, stream);
        red(R_B16LD, Pb, NC, GG, 4, nullptr, nullptr, 0, nullptr, Ubig, 2*GG, hh*GG,
            interact, 1.f, stream);
    }
    sk(Ubig, 2*GG, ciGbigT, 2*GG, Pb, NC, GG, 2*GG, 4, interact, stream);
    red(R_ACCG, Pb, NC, GG, 4, nullptr, nullptr, 0, out, nullptr, GG, 0,
        interact, 1.0f/1024.f, stream);
}